// Round 18
// baseline (676.803 us; speedup 1.0000x reference)
//
#include <hip/hip_runtime.h>
#include <hip/hip_bf16.h>
#include <hip/hip_fp16.h>

__device__ __forceinline__ float eluf(float x){ return x > 0.f ? x : expm1f(x); }

typedef __attribute__((ext_vector_type(8))) short bf16x8;
typedef __attribute__((ext_vector_type(4))) short bf16x4;
typedef __attribute__((ext_vector_type(8))) _Float16 f16x8;
typedef __attribute__((ext_vector_type(4))) float f32x4;

__device__ __forceinline__ unsigned int bf16r(float f){
  unsigned int u = __float_as_uint(f);
  return (u + 0x7FFFu + ((u >> 16) & 1u)) >> 16;   // RNE
}

__device__ __forceinline__ unsigned short f16b(float f){
  __half h = __float2half(f);                       // RNE
  return __half_as_ushort(h);
}

// 8-byte-aligned bf16x8 load as two b64 reads (for LDS rows that are 8B- but not 16B-aligned)
__device__ __forceinline__ bf16x8 ldu16x8(const unsigned short* p){
  bf16x4 a = *(const bf16x4*)p;
  bf16x4 b = *(const bf16x4*)(p + 4);
  return __builtin_shufflevector(a, b, 0,1,2,3,4,5,6,7);
}

// LDS row stride helper
constexpr int pad_stride(int wp){
  int s = (wp + 3) & ~3;
  return (s % 8 == 0) ? s + 4 : s;
}

// ---------------- conv1 pass A: stats partials (no global atomics) ----------------
__global__ __launch_bounds__(256)
void conv1_stats(const float* __restrict__ in, const float* __restrict__ w,
                 const float* __restrict__ bias, float* __restrict__ part)
{
  constexpr int WPL = pad_stride(30);   // 36
  __shared__ __align__(16) float img[2][30*WPL];
  __shared__ float wl[2][8*9];
  __shared__ float sred[8], qred[8];
  const int b = blockIdx.x, gy = blockIdx.y, o0 = gy*8, t = threadIdx.x;
  const int ol = t & 7, y = t >> 3;
  if (t < 8){ sred[t] = 0.f; qred[t] = 0.f; }
  for (int idx = t; idx < 2*30*WPL; idx += 256) ((float*)img)[idx] = 0.f;
  __syncthreads();
  for (int idx = t; idx < 2*784; idx += 256){
    int cl = idx/784, r = idx%784;
    img[cl][(r/28 + 1)*WPL + (r%28) + 1] = in[((long long)b*2)*784 + idx];
  }
  if (t < 144){
    int cl = t/72, r = t%72;
    wl[cl][r] = w[(((long long)(o0 + r/9))*2 + cl)*9 + (r%9)];
  }
  __syncthreads();
  const bool active = (y < 28);
  float acc[28];
  #pragma unroll
  for (int x = 0; x < 28; x++) acc[x] = 0.f;
  if (active){
    for (int cl = 0; cl < 2; cl++){
      #pragma unroll
      for (int ky = 0; ky < 3; ky++){
        const float* row = &img[cl][(y+ky)*WPL];
        float rin[30];
        #pragma unroll
        for (int q = 0; q < 7; q++){
          float4 v = ((const float4*)row)[q];
          rin[4*q+0]=v.x; rin[4*q+1]=v.y; rin[4*q+2]=v.z; rin[4*q+3]=v.w;
        }
        rin[28] = row[28]; rin[29] = row[29];
        #pragma unroll
        for (int kx = 0; kx < 3; kx++){
          float wv = wl[cl][ol*9 + ky*3 + kx];
          #pragma unroll
          for (int x = 0; x < 28; x++) acc[x] += wv * rin[x+kx];
        }
      }
    }
  }
  const int og = o0 + ol;
  float sv = 0.f, qv = 0.f;
  if (active){
    float bv = bias[og];
    #pragma unroll
    for (int x = 0; x < 28; x++){
      float v = acc[x] + bv;
      sv += v; qv += v*v;
    }
  }
  #pragma unroll
  for (int d = 32; d >= 8; d >>= 1){
    sv += __shfl_down(sv, d);
    qv += __shfl_down(qv, d);
  }
  if ((t & 63) < 8){ atomicAdd(&sred[ol], sv); atomicAdd(&qred[ol], qv); }   // LDS atomics (cheap)
  __syncthreads();
  if (t < 8){
    float* pp = part + ((long long)(b*8 + gy))*16;
    pp[t]     = sred[t];
    pp[t + 8] = qred[t];
  }
}

// ---------------- conv1 stats reduce: 2048x16 partials -> s1/q1 (1 block) ----------------
__global__ __launch_bounds__(256)
void conv1_reduce(const float* __restrict__ part, float* __restrict__ sum, float* __restrict__ sq)
{
  __shared__ float ss[256], qq[256];
  const int t = threadIdx.x;
  const int c = t & 63, seg = t >> 6;        // channel c, batch segment seg (4 x 64)
  const int gy = c >> 3, ol = c & 7;
  float sv = 0.f, qv = 0.f;
  for (int b = seg*64; b < seg*64 + 64; b++){
    const float* pp = part + ((long long)(b*8 + gy))*16;
    sv += pp[ol];
    qv += pp[ol + 8];
  }
  ss[t] = sv; qq[t] = qv;
  __syncthreads();
  if (t < 64){
    sum[c] = ss[t] + ss[t+64] + ss[t+128] + ss[t+192];
    sq[c]  = qq[t] + qq[t+64] + qq[t+128] + qq[t+192];
  }
}

// ---------------- conv1 pass B: recompute conv + bn1 + elu + avgpool -> p1 (LDS-staged coalesced out) ----------------
__global__ __launch_bounds__(256)
void conv1_pool(const float* __restrict__ in, const float* __restrict__ w,
                const float* __restrict__ bias, const float* __restrict__ g,
                const float* __restrict__ bb, const float* __restrict__ sum,
                const float* __restrict__ sq, float* __restrict__ out)
{
  constexpr int WPL = pad_stride(30);   // 36
  constexpr int PST = 197;              // pout row stride (197 mod 32 = 5 -> bank-spread)
  __shared__ __align__(16) float img[2][30*WPL];
  __shared__ float wl[2][16*9];
  __shared__ float pout[16*PST];
  const int b = blockIdx.x, o0 = blockIdx.y*16, t = threadIdx.x;
  const int ol = t & 15, yp = t >> 4;
  for (int idx = t; idx < 2*30*WPL; idx += 256) ((float*)img)[idx] = 0.f;
  __syncthreads();
  for (int idx = t; idx < 2*784; idx += 256){
    int cl = idx/784, r = idx%784;
    img[cl][(r/28 + 1)*WPL + (r%28) + 1] = in[((long long)b*2)*784 + idx];
  }
  for (int idx = t; idx < 288; idx += 256){
    int cl = idx/144, r = idx%144;
    wl[cl][r] = w[(((long long)(o0 + r/9))*2 + cl)*9 + (r%9)];
  }
  __syncthreads();
  if (yp < 14){
    float accA[28], accB[28];
    #pragma unroll
    for (int x = 0; x < 28; x++){ accA[x] = 0.f; accB[x] = 0.f; }
    for (int cl = 0; cl < 2; cl++){
      #pragma unroll
      for (int ky = 0; ky < 3; ky++){
        const float* rowA = &img[cl][(2*yp+ky)*WPL];
        const float* rowB = rowA + WPL;
        float ra[30], rb[30];
        #pragma unroll
        for (int q = 0; q < 7; q++){
          float4 va = ((const float4*)rowA)[q];
          ra[4*q+0]=va.x; ra[4*q+1]=va.y; ra[4*q+2]=va.z; ra[4*q+3]=va.w;
          float4 vb = ((const float4*)rowB)[q];
          rb[4*q+0]=vb.x; rb[4*q+1]=vb.y; rb[4*q+2]=vb.z; rb[4*q+3]=vb.w;
        }
        ra[28]=rowA[28]; ra[29]=rowA[29];
        rb[28]=rowB[28]; rb[29]=rowB[29];
        #pragma unroll
        for (int kx = 0; kx < 3; kx++){
          float wv = wl[cl][ol*9 + ky*3 + kx];
          #pragma unroll
          for (int x = 0; x < 28; x++){
            accA[x] += wv * ra[x+kx];
            accB[x] += wv * rb[x+kx];
          }
        }
      }
    }
    const int og = o0 + ol;
    const float bv = bias[og];
    const float invN = 1.f/200704.f;
    float mean = sum[og]*invN;
    float var  = sq[og]*invN - mean*mean;
    float sc = g[og] * rsqrtf(var + 1e-5f);
    float sh = bb[og] - mean*sc;
    float* po = &pout[ol*PST + yp*14];
    #pragma unroll
    for (int xp = 0; xp < 14; xp++){
      float acc = eluf(sc*(accA[2*xp]   + bv) + sh);
      acc      += eluf(sc*(accA[2*xp+1] + bv) + sh);
      acc      += eluf(sc*(accB[2*xp]   + bv) + sh);
      acc      += eluf(sc*(accB[2*xp+1] + bv) + sh);
      po[xp] = acc * 0.25f;
    }
  }
  __syncthreads();
  // coalesced block-wide store: 3136 contiguous floats at p1[b][o0..o0+16][..]
  float* gbase = out + ((long long)b*64 + o0)*196;
  for (int idx = t; idx < 3136; idx += 256)
    gbase[idx] = pout[(idx/196)*PST + idx%196];
}

// ---------------- fused offsets(18, raw) + mask(9, sigmoid) 3x3 pad-1 conv ----------------
template<int CIN,int H,int W,int NZ>
__global__ __launch_bounds__(256)
void offmask_tiled(const float* __restrict__ in, const float* __restrict__ pw,
                   const float* __restrict__ pb, const float* __restrict__ mw,
                   const float* __restrict__ mb, float* __restrict__ om)
{
  constexpr int Hz  = H/NZ;
  constexpr int HP  = Hz + 2;
  constexpr int WP  = W + 2;
  constexpr int WPL = pad_stride(WP);
  __shared__ __align__(16) float img[CIN*HP*WPL];
  const int b = blockIdx.x;
  const int z = blockIdx.y;
  const int t = threadIdx.x;
  for (int i = t; i < CIN*HP*WPL; i += 256) img[i] = 0.f;
  __syncthreads();
  const int base = z*Hz - 1;                       // padded row 0 <-> global row `base`
  const int gy0  = (base < 0) ? 0 : base;
  const int gy1  = (z*Hz + Hz + 1 > H) ? H : z*Hz + Hz + 1;
  const int nrows = gy1 - gy0;
  for (int i = t; i < CIN*nrows*W; i += 256){
    int x = i % W; int r = i / W;
    int row = r % nrows; int c = r / nrows;
    int gy = gy0 + row;
    img[(c*HP + (gy - base))*WPL + (x+1)] = in[((long long)b*CIN + c)*(H*W) + gy*W + x];
  }
  __syncthreads();
  const int o  = t & 31;
  const int yl = t >> 5;
  const int y  = z*Hz + yl;
  if (o < 27 && yl < Hz && y < H){
    float acc[W];
    #pragma unroll
    for (int x = 0; x < W; x++) acc[x] = 0.f;
    const float* wsrc = (o < 18) ? (pw + (long long)o*CIN*9) : (mw + (long long)(o-18)*CIN*9);
    for (int c = 0; c < CIN; c++){
      const float* wc = wsrc + c*9;
      float4 wa = *(const float4*)wc;
      float4 wbv = *(const float4*)(wc+4);
      float w8 = wc[8];
      const float* rm = &img[(c*HP + yl  )*WPL];
      const float* r0 = &img[(c*HP + yl+1)*WPL];
      const float* rp = &img[(c*HP + yl+2)*WPL];
      #pragma unroll
      for (int x = 0; x < W; x++){
        acc[x] += wa.x*rm[x] + wa.y*rm[x+1] + wa.z*rm[x+2]
                + wa.w*r0[x] + wbv.x*r0[x+1] + wbv.y*r0[x+2]
                + wbv.z*rp[x] + wbv.w*rp[x+1] + w8*rp[x+2];
      }
    }
    float bv = (o < 18) ? pb[o] : mb[o-18];
    float* po = om + (((long long)b*27 + o)*H + y)*W;
    #pragma unroll
    for (int x = 0; x < W; x++){
      float v = acc[x] + bv;
      if (o >= 18) v = 1.f/(1.f + expf(-v));
      po[x] = v;
    }
  }
}

// ---------------- conv4 (64->2, 7x7, pad 1): block-per-image LDS kernel ----------------
__global__ __launch_bounds__(256)
void conv4_tiled(const float* __restrict__ in, const float* __restrict__ w,
                 const float* __restrict__ bias, float* __restrict__ out)
{
  __shared__ __align__(16) float img[64*9*12];   // padded [c][9][12], 27.6KB
  __shared__ float wl[1152];                     // w[2][64][9], 4.6KB
  const int b = blockIdx.x, t = threadIdx.x;
  for (int i = t; i < 64*108; i += 256) img[i] = 0.f;
  __syncthreads();
  for (int i = t; i < 64*49; i += 256){
    int px = i % 49, c = i / 49;
    img[(c*9 + px/7 + 1)*12 + (px%7) + 1] = in[((long long)b*64 + c)*49 + px];
  }
  for (int i = t; i < 1152; i += 256) wl[i] = w[i];
  __syncthreads();
  const int o  = t >> 7;
  const int px = t & 127;
  if (px < 49){
    int y = px/7, x = px%7;
    float acc = bias[o];
    const float* wo = &wl[o*576];
    for (int c = 0; c < 64; c++){
      const float* rm = &img[(c*9 + y)*12 + x];
      const float* r0 = rm + 12;
      const float* rp = rm + 24;
      const float* wc = wo + c*9;
      acc += wc[0]*rm[0]+wc[1]*rm[1]+wc[2]*rm[2]
           + wc[3]*r0[0]+wc[4]*r0[1]+wc[5]*r0[2]
           + wc[6]*rp[0]+wc[7]*rp[1]+wc[8]*rp[2];
    }
    out[((long long)b*2 + o)*49 + px] = acc;
  }
}

// ---------------- conv3 weights -> bf16 wb[kk][o][c] ----------------
__global__ void wconv3_bf16_kernel(const float* __restrict__ w, unsigned short* __restrict__ wb)
{
  int idx = blockIdx.x*256 + threadIdx.x;
  if (idx >= 147456) return;
  int kk = idx >> 14;
  int r  = idx & 16383;
  int o  = r >> 7, c = r & 127;
  wb[idx] = (unsigned short)bf16r(w[((long long)o*128 + c)*9 + kk]);
}

// ---------------- bn2 + elu + bf16 pack into padded [b][ch][hp=256][64] layout ----------------
__global__ void bn2_pack_kernel(const float* __restrict__ a2, const float* __restrict__ g,
                                const float* __restrict__ bb, const float* __restrict__ sum,
                                const float* __restrict__ sq, unsigned int* __restrict__ a2b)
{
  int idx = blockIdx.x*256 + threadIdx.x;
  if (idx >= 4194304) return;                 // 256 b x 2 ch x 256 hp x 32 u32
  int c2 = idx & 31; int r = idx >> 5;
  int hp = r & 255; r >>= 8;
  int ch = r & 1; int b = r >> 1;
  int row = hp >> 4, col = hp & 15;
  unsigned val = 0u;
  if (row >= 1 && row <= 14 && col >= 1 && col <= 14){
    int px = (row-1)*14 + (col-1);
    int c = ch*64 + 2*c2;
    const float invN = 1.f/50176.f;
    float m0 = sum[c]*invN,     m1 = sum[c+1]*invN;
    float v0 = sq[c]*invN - m0*m0, v1 = sq[c+1]*invN - m1*m1;
    float sc0 = g[c]*rsqrtf(v0 + 1e-5f), sc1 = g[c+1]*rsqrtf(v1 + 1e-5f);
    float sh0 = bb[c] - m0*sc0, sh1 = bb[c+1] - m1*sc1;
    float x0 = a2[((long long)b*128 + c)*196 + px];
    float x1 = a2[((long long)b*128 + c + 1)*196 + px];
    float e0 = eluf(sc0*x0 + sh0), e1 = eluf(sc1*x1 + sh1);
    val = bf16r(e0) | (bf16r(e1) << 16);
  }
  a2b[idx] = val;
}

// ---------------- conv3 via bf16 MFMA, 64-o tile, pre-packed bf16 input ----------------
__global__ __launch_bounds__(256)
void conv3_mfma2(const unsigned short* __restrict__ a2b, const unsigned short* __restrict__ wb,
                 const float* __restrict__ bias, float* __restrict__ out,
                 float* __restrict__ sum, float* __restrict__ sq)
{
  constexpr int RS = 72;                       // u16 per hp row: 64 ch + 8 pad
  __shared__ __align__(16) unsigned short img[256*RS];
  __shared__ float sred[64], qred[64];
  const int b  = blockIdx.x;
  const int o0 = blockIdx.y * 64;
  const int t  = threadIdx.x;
  const int lane = t & 63, wv = t >> 6;
  const int l15 = lane & 15, q = lane >> 4;
  const int ntile = (wv == 0) ? 4 : 3;
  if (t < 64){ sred[t] = 0.f; qred[t] = 0.f; }
  int rbase[4];
  #pragma unroll
  for (int ti = 0; ti < 4; ti++){
    int px = (wv + ti*4)*16 + l15;
    int pxe = px < 196 ? px : 195;
    rbase[ti] = (pxe/14)*16 + (pxe%14);
  }
  f32x4 acc[4][4];
  #pragma unroll
  for (int og = 0; og < 4; og++)
    #pragma unroll
    for (int ti = 0; ti < 4; ti++) acc[og][ti] = (f32x4){0.f,0.f,0.f,0.f};
  for (int ch = 0; ch < 2; ch++){
    __syncthreads();                            // prev MFMA reads done
    const unsigned short* src = a2b + ((long long)(b*2 + ch))*16384;
    for (int it = t; it < 2048; it += 256){     // 2048 x 16B chunks (256 rows x 128B)
      int r = it >> 3, j = it & 7;
      uint4 v = *(const uint4*)(src + r*64 + j*8);
      *(uint4*)&img[r*RS + j*8] = v;
    }
    __syncthreads();
    #pragma unroll
    for (int kk = 0; kk < 9; kk++){
      int dh = (kk/3)*16 + (kk%3);
      #pragma unroll
      for (int ks = 0; ks < 2; ks++){
        bf16x8 bf[4];
        #pragma unroll
        for (int ti = 0; ti < 4; ti++)
          if (ti < ntile)
            bf[ti] = *(const bf16x8*)&img[(rbase[ti]+dh)*RS + ks*32 + q*8];
        #pragma unroll
        for (int og = 0; og < 4; og++){
          const unsigned short* wp = wb + (((long long)kk*128 + o0 + og*16 + l15)*128 + ch*64 + ks*32 + q*8);
          bf16x8 af = *(const bf16x8*)wp;
          #pragma unroll
          for (int ti = 0; ti < 4; ti++)
            if (ti < ntile)
              acc[og][ti] = __builtin_amdgcn_mfma_f32_16x16x32_bf16(af, bf[ti], acc[og][ti], 0, 0, 0);
        }
      }
    }
  }
  // epilogue: out = acc + bias (raw, bn3 applied later) + fused bn3 stats
  float svl[4][4], qvl[4][4];
  #pragma unroll
  for (int og = 0; og < 4; og++)
    #pragma unroll
    for (int r = 0; r < 4; r++){ svl[og][r] = 0.f; qvl[og][r] = 0.f; }
  #pragma unroll
  for (int og = 0; og < 4; og++){
    #pragma unroll
    for (int ti = 0; ti < 4; ti++){
      if (ti < ntile){
        int px = (wv + ti*4)*16 + l15;
        if (px < 196){
          #pragma unroll
          for (int r = 0; r < 4; r++){
            int o = o0 + og*16 + q*4 + r;
            float v = acc[og][ti][r] + bias[o];
            out[((long long)b*128 + o)*196 + px] = v;
            svl[og][r] += v; qvl[og][r] += v*v;
          }
        }
      }
    }
  }
  #pragma unroll
  for (int og = 0; og < 4; og++)
    #pragma unroll
    for (int r = 0; r < 4; r++)
      #pragma unroll
      for (int m = 1; m < 16; m <<= 1){
        svl[og][r] += __shfl_xor(svl[og][r], m);
        qvl[og][r] += __shfl_xor(qvl[og][r], m);
      }
  if (l15 == 0){
    #pragma unroll
    for (int og = 0; og < 4; og++)
      #pragma unroll
      for (int r = 0; r < 4; r++){
        atomicAdd(&sred[og*16 + q*4 + r], svl[og][r]);
        atomicAdd(&qred[og*16 + q*4 + r], qvl[og][r]);
      }
  }
  __syncthreads();
  if (t < 64){ atomicAdd(&sum[o0 + t], sred[t]); atomicAdd(&sq[o0 + t], qred[t]); }
}

// ---------------- stride-2 transpose conv, parity-decomposed (kept for convT4m) ----------------
template<int HIN,int WIN,int CIN,int COUT,bool DO_ELU>
__global__ __launch_bounds__(256)
void convt_s2_tiled(const float* __restrict__ in, const float* __restrict__ w,
                    const float* __restrict__ bias, float* __restrict__ out)
{
  constexpr int HOUT = 2*HIN - 1, WOUT = 2*WIN - 1;
  constexpr int RS = 20;
  __shared__ __align__(16) float img[17*RS];
  __shared__ float wl[16][10];
  const int b  = blockIdx.x;
  const int o0 = blockIdx.y * 16;
  const int t  = threadIdx.x;
  const int ol = t & 15, yb = t >> 4;
  for (int idx = t; idx < 17*RS; idx += 256) img[idx] = 0.f;
  float accA[WOUT], accB[WOUT];
  #pragma unroll
  for (int x = 0; x < WOUT; x++){ accA[x] = 0.f; accB[x] = 0.f; }
  for (int c = 0; c < CIN; c++){
    __syncthreads();
    for (int idx = t; idx < HIN*WIN; idx += 256)
      img[(idx/WIN)*RS + idx%WIN] = in[((long long)b*CIN + c)*HIN*WIN + idx];
    if (t < 144)
      wl[t/9][t%9] = w[(((long long)c*COUT + o0 + t/9)*3 + (t%9)/3)*3 + (t%9)%3];
    __syncthreads();
    float ru[16], rd[16];
    #pragma unroll
    for (int q = 0; q < 4; q++){
      float4 va = ((const float4*)&img[yb*RS])[q];
      ru[4*q+0]=va.x; ru[4*q+1]=va.y; ru[4*q+2]=va.z; ru[4*q+3]=va.w;
      float4 vb = ((const float4*)&img[(yb+1)*RS])[q];
      rd[4*q+0]=vb.x; rd[4*q+1]=vb.y; rd[4*q+2]=vb.z; rd[4*q+3]=vb.w;
    }
    float w00=wl[ol][0], w01=wl[ol][1], w02=wl[ol][2];
    float w10=wl[ol][3], w11=wl[ol][4], w12=wl[ol][5];
    float w20=wl[ol][6], w21=wl[ol][7], w22=wl[ol][8];
    #pragma unroll
    for (int v = 0; v < WIN; v++){
      accA[2*v] += w11*ru[v];
      accB[2*v] += w21*ru[v] + w01*rd[v];
    }
    #pragma unroll
    for (int v = 0; v < WIN-1; v++){
      accA[2*v+1] += w12*ru[v] + w10*ru[v+1];
      accB[2*v+1] += w22*ru[v] + w20*ru[v+1] + w02*rd[v] + w00*rd[v+1];
    }
  }
  const int og = o0 + ol;
  const float bv = bias[og];
  const int yA = 2*yb, yB = 2*yb + 1;
  if (yA < HOUT){
    float* po = out + (((long long)b*COUT + og)*HOUT + yA)*WOUT;
    #pragma unroll
    for (int x = 0; x < WOUT; x++){ float v = accA[x] + bv; po[x] = DO_ELU ? eluf(v) : v; }
  }
  if (yB < HOUT){
    float* po = out + (((long long)b*COUT + og)*HOUT + yB)*WOUT;
    #pragma unroll
    for (int x = 0; x < WOUT; x++){ float v = accB[x] + bv; po[x] = DO_ELU ? eluf(v) : v; }
  }
}

// ---------------- deform weights -> fp16, [ch][o][160] (K = kk*16 + p; pad 144..159 = 0) ----------------
// Position p within a 16-channel chunk holds channel (p>>2) + 4*(p&3)  (4x4 transpose),
// matching deform_mfma's bank-conflict-free plane-per-lane gather order.
__global__ void wdeform_f16_kernel(const float* __restrict__ w, unsigned short* __restrict__ wf,
                                   int CIN, int COUT)
{
  int n = (CIN/16)*COUT*160;
  int idx = blockIdx.x*256 + threadIdx.x;
  if (idx >= n) return;
  int ch = idx / (COUT*160);
  int r  = idx % (COUT*160);
  int o  = r / 160, k = r % 160;
  unsigned short h = 0;
  if (k < 144){
    int kk = k >> 4, cp = k & 15;
    int cl = (cp >> 2) + 4*(cp & 3);          // position -> channel (involutive with writer)
    h = f16b(w[((long long)o*CIN + ch*16 + cl)*9 + kk]);
  }
  wf[idx] = h;
}

// ---------------- convT3m flipped weights -> hi/lo bf16, [kk][o=64][c=128] ----------------
__global__ void wconvt3m_split_kernel(const float* __restrict__ w, unsigned short* __restrict__ whi,
                                      unsigned short* __restrict__ wlo)
{
  int idx = blockIdx.x*256 + threadIdx.x;
  if (idx >= 73728) return;
  int kk = idx / 8192;
  int r  = idx % 8192;
  int o  = r >> 7, c = r & 127;
  int ky = kk/3, kx = kk%3;
  float v = w[(((long long)c*64 + o)*3 + (2-ky))*3 + (2-kx)];
  unsigned hu = bf16r(v);
  float res = v - __uint_as_float(hu << 16);
  whi[idx] = (unsigned short)hu;
  wlo[idx] = (unsigned short)bf16r(res);
}

// ---------------- convT2m weights -> hi/lo bf16, [kk=wky*3+wkx][o=32][c=64] ----------------
__global__ void wconvt2m_split_kernel(const float* __restrict__ w, unsigned short* __restrict__ whi,
                                      unsigned short* __restrict__ wlo)
{
  int idx = blockIdx.x*256 + threadIdx.x;
  if (idx >= 18432) return;
  int kk = idx / 2048;
  int r  = idx % 2048;
  int o  = r >> 6, c = r & 63;
  float v = w[((long long)c*32 + o)*9 + kk];
  unsigned hu = bf16r(v);
  float res = v - __uint_as_float(hu << 16);
  whi[idx] = (unsigned short)hu;
  wlo[idx] = (unsigned short)bf16r(res);
}

// ---------------- deformable conv via fp16 MFMA (single-product; ~2^-11 rel) ----------------
// v4: plane-transposed gather (lane c4 owns planes {c4, c4+4, c4+8, c4+12}; bank bases
// {0,4,8,12} for HW=196 -> conflict-free within 4-lane group; weights permuted to match).
// Direct float4 global->LDS staging.
template<int CIN,int COUT,int H,int W,int PXT,int NT,int NPT,int OTW>
__global__ __launch_bounds__(256)
void deform_mfma(const float* __restrict__ x, const float* __restrict__ om,
                 const unsigned short* __restrict__ wf,
                 float* __restrict__ out, float* __restrict__ sum, float* __restrict__ sq)
{
  constexpr int HW  = H*W;
  constexpr int CC  = 16;          // channels per chunk
  constexpr int NCH = CIN/CC;
  constexpr int GS  = 168;         // u16 per G row: 144 K + 16 zero-pad + 8 bank-pad
  constexpr int KP  = 160;         // padded K per chunk (5 MFMA K-steps of 32)
  __shared__ __align__(16) float simg[CC*HW];
  __shared__ __align__(16) unsigned short Gf[PXT*GS];
  __shared__ __align__(16) float kwv[PXT*9*4];     // aliased as sred/qred in epilogue
  __shared__ __align__(4)  unsigned char kidx[PXT*9*4];
  const int tile = blockIdx.x % NT;
  const int b    = blockIdx.x / NT;
  const int t    = threadIdx.x;
  const int lane = t & 63, wv = t >> 6;
  const int l15  = lane & 15, q = lane >> 4;
  const int Hp = H + 2, Wp = W + 2;
  for (int idx = t; idx < PXT*16; idx += 256){
    int px = idx >> 4, k = 144 + (idx & 15);
    Gf[px*GS + k] = 0;
  }
  for (int it = t; it < PXT*9; it += 256){
    int px = it / 9, kk = it % 9;
    int p = tile*PXT + px;
    float w0=0.f,w1=0.f,w2=0.f,w3=0.f;
    int i0=0,i1=0,i2=0,i3=0;
    if (p < HW){
      int i = p / W, j = p % W;
      long long base = ((long long)b*27)*HW + p;
      float offx = om[base + (long long)kk*HW];
      float offy = om[base + (long long)(9+kk)*HW];
      float mk   = om[base + (long long)(18+kk)*HW];
      float pnx = (float)(kk/3) - 1.f;
      float pny = (float)(kk%3) - 1.f;
      float px_ = fminf(fmaxf((float)(i+1) + pnx + offx, 0.f), (float)(Hp-1));
      float py_ = fminf(fmaxf((float)(j+1) + pny + offy, 0.f), (float)(Wp-1));
      float fx = floorf(px_), fy = floorf(py_);
      float x0 = fmaxf(fx, 0.f), y0 = fmaxf(fy, 0.f);
      float x1c = fminf(fx + 1.f, (float)(Hp-1));
      float y1c = fminf(fy + 1.f, (float)(Wp-1));
      float glt = (1.f + (x0 - px_)) * (1.f + (y0 - py_));
      float grb = (1.f - (x1c - px_)) * (1.f - (y1c - py_));
      float glb = (1.f + (x0 - px_)) * (1.f - (y1c - py_));
      float grt = (1.f - (x1c - px_)) * (1.f + (y0 - py_));
      int ax0=(int)x0, ay0=(int)y0, ax1=(int)x1c, ay1=(int)y1c;
      if (ax0>=1 && ax0<=H && ay0>=1 && ay0<=W){ w0 = glt*mk; i0 = (ax0-1)*W + (ay0-1); }
      if (ax1>=1 && ax1<=H && ay1>=1 && ay1<=W){ w1 = grb*mk; i1 = (ax1-1)*W + (ay1-1); }
      if (ax0>=1 && ax0<=H && ay1>=1 && ay1<=W){ w2 = glb*mk; i2 = (ax0-1)*W + (ay1-1); }
      if (ax1>=1 && ax1<=H && ay0>=1 && ay0<=W){ w3 = grt*mk; i3 = (ax1-1)*W + (ay0-1); }
    }
    int b4 = it*4;
    kwv[b4+0]=w0; kwv[b4+1]=w1; kwv[b4+2]=w2; kwv[b4+3]=w3;
    kidx[b4+0]=(unsigned char)i0; kidx[b4+1]=(unsigned char)i1;
    kidx[b4+2]=(unsigned char)i2; kidx[b4+3]=(unsigned char)i3;
  }
  int grow[NPT];
  #pragma unroll
  for (int pt = 0; pt < NPT; pt++){
    int p = pt*16 + l15; if (p > PXT-1) p = PXT-1;
    grow[pt] = p*GS;
  }
  f32x4 acc[OTW][NPT];
  #pragma unroll
  for (int ot = 0; ot < OTW; ot++)
    #pragma unroll
    for (int pt = 0; pt < NPT; pt++) acc[ot][pt] = (f32x4){0.f,0.f,0.f,0.f};

  for (int ch = 0; ch < NCH; ch++){
    __syncthreads();
    // vectorized chunk staging: 16 contiguous channel planes, 16B-aligned
    {
      const float4* src = (const float4*)&x[((long long)b*CIN + ch*CC)*HW];
      for (int idx = t; idx < (CC*HW)/4; idx += 256)
        ((float4*)simg)[idx] = src[idx];
    }
    __syncthreads();
    // 4-channel gather iterations; lane c4 owns planes {c4, c4+4, c4+8, c4+12}
    for (int it = t; it < PXT*9*4; it += 256){
      int c4 = it & 3; int r = it >> 2;
      int kk = r % 9, px = r / 9;
      int b4 = (px*9 + kk)*4;
      float4 wv4 = *(const float4*)&kwv[b4];
      uchar4 id4 = *(const uchar4*)&kidx[b4];
      const float* pl = &simg[c4*HW];
      unsigned long long uo = 0ull;
      #pragma unroll
      for (int u = 0; u < 4; u++){
        const float* im = pl + u*(4*HW);   // channel c4 + 4u
        float v = wv4.x*im[id4.x] + wv4.y*im[id4.y] + wv4.z*im[id4.z] + wv4.w*im[id4.w];
        uo |= (unsigned long long)f16b(v) << (16*u);
      }
      *(unsigned long long*)&Gf[px*GS + kk*16 + 4*c4] = uo;   // positions 4c4+u <-> channels c4+4u (weights permuted)
    }
    __syncthreads();
    const unsigned short* wh = wf + (long long)ch*COUT*KP;
    #pragma unroll
    for (int st = 0; st < 5; st++){
      f16x8 bh[NPT];
      #pragma unroll
      for (int pt = 0; pt < NPT; pt++)
        bh[pt] = *(const f16x8*)&Gf[grow[pt] + st*32 + q*8];
      #pragma unroll
      for (int ot = 0; ot < OTW; ot++){
        int o = (wv*OTW + ot)*16 + l15;
        f16x8 ah = *(const f16x8*)&wh[o*KP + st*32 + q*8];
        #pragma unroll
        for (int pt = 0; pt < NPT; pt++)
          acc[ot][pt] = __builtin_amdgcn_mfma_f32_16x16x32_f16(ah, bh[pt], acc[ot][pt], 0, 0, 0);
      }
    }
  }
  float* sred = kwv;
  float* qred = kwv + COUT;
  float sv[OTW][4], qv[OTW][4];
  #pragma unroll
  for (int ot = 0; ot < OTW; ot++)
    #pragma unroll
    for (int r = 0; r < 4; r++){ sv[ot][r] = 0.f; qv[ot][r] = 0.f; }
  #pragma unroll
  for (int ot = 0; ot < OTW; ot++){
    #pragma unroll
    for (int pt = 0; pt < NPT; pt++){
      int p = pt*16 + l15;
      int gp = tile*PXT + p;
      bool ok = (p < PXT) && (gp < HW);
      #pragma unroll
      for (int r = 0; r < 4; r++){
        if (ok){
          int o = (wv*OTW + ot)*16 + q*4 + r;
          float v = acc[ot][pt][r];
          out[((long long)b*COUT + o)*HW + gp] = v;
          sv[ot][r] += v; qv[ot][r] += v*v;
        }
      }
    }
  }
  #pragma unroll
  for (int ot = 0; ot < OTW; ot++)
    #pragma unroll
    for (int r = 0; r < 4; r++)
      #pragma unroll
      for (int m = 1; m < 16; m <<= 1){
        sv[ot][r] += __shfl_xor(sv[ot][r], m);
        qv[ot][r] += __shfl_xor(qv[ot][r], m);
      }
  __syncthreads();
  if (t < COUT){ sred[t] = 0.f; qred[t] = 0.f; }
  __syncthreads();
  if (l15 == 0){
    #pragma unroll
    for (int ot = 0; ot < OTW; ot++)
      #pragma unroll
      for (int r = 0; r < 4; r++){
        int o = (wv*OTW + ot)*16 + q*4 + r;
        atomicAdd(&sred[o], sv[ot][r]);
        atomicAdd(&qred[o], qv[ot][r]);
      }
  }
  __syncthreads();
  if (t < COUT){ atomicAdd(&sum[t], sred[t]); atomicAdd(&sq[t], qred[t]); }
}

// ---------------- convT3m (128->64, 13x13 -> 15x15 pad-2 flipped conv) via bf16 MFMA hi/lo ----------------
// RS=44: row stride 22 words, gcd(22,32)=2 -> 16 distinct banks per 16-lane group (was
// RS=40: gcd(20,32)=4, 8 banks, 5.04M conflict-cycles). Rows now 8B-aligned only ->
// operand loads via two b64 reads (ldu16x8).
__global__ __launch_bounds__(256)
void convt3m_mfma(const float* __restrict__ in, const unsigned short* __restrict__ wbhi,
                  const unsigned short* __restrict__ wblo, const float* __restrict__ bias,
                  float* __restrict__ out)
{
  constexpr int RS = 44;                 // u16 per hp row: 32 ch + 12 pad
  __shared__ __align__(16) unsigned short gh[289*RS];
  __shared__ __align__(16) unsigned short gl[289*RS];
  const int b  = blockIdx.x;
  const int zt = blockIdx.y;             // 0: tiles 0..7, 1: tiles 8..14
  const int t  = threadIdx.x;
  const int lane = t & 63, wv = t >> 6;
  const int l15 = lane & 15, q = lane >> 4;
  const int og0 = (wv & 1)*2;            // o-groups og0, og0+1
  const int tb  = zt*8 + (wv >> 1)*4;    // first tile for this wave
  const int ntl = (zt == 0) ? 4 : ((wv >> 1) ? 3 : 4);
  f32x4 acc[2][4];
  #pragma unroll
  for (int ot = 0; ot < 2; ot++)
    #pragma unroll
    for (int ti = 0; ti < 4; ti++) acc[ot][ti] = (f32x4){0.f,0.f,0.f,0.f};
  {
    unsigned* zg = (unsigned*)gh; unsigned* zl = (unsigned*)gl;
    for (int idx = t; idx < 289*RS/2; idx += 256){ zg[idx] = 0u; zl[idx] = 0u; }
  }
  for (int cq = 0; cq < 4; cq++){
    __syncthreads();
    for (int idx = t; idx < 16*169; idx += 256){
      int c2 = idx / 169, px = idx % 169;
      int c = 2*c2;
      const float* ip = in + ((long long)b*128 + cq*32 + c)*169 + px;
      float f0 = ip[0];
      float f1 = ip[169];
      unsigned h0 = bf16r(f0); unsigned l0 = bf16r(f0 - __uint_as_float(h0<<16));
      unsigned h1 = bf16r(f1); unsigned l1 = bf16r(f1 - __uint_as_float(h1<<16));
      int hp = (px/13 + 2)*17 + (px%13) + 2;
      *(unsigned*)&gh[hp*RS + c] = h0 | (h1<<16);
      *(unsigned*)&gl[hp*RS + c] = l0 | (l1<<16);
    }
    __syncthreads();
    #pragma unroll
    for (int kk = 0; kk < 9; kk++){
      const long long wo = ((long long)kk*64)*128 + (long long)cq*32 + q*8;
      bf16x8 ah0 = *(const bf16x8*)&wbhi[wo + (long long)(og0*16 + l15)*128];
      bf16x8 al0 = *(const bf16x8*)&wblo[wo + (long long)(og0*16 + l15)*128];
      bf16x8 ah1 = *(const bf16x8*)&wbhi[wo + (long long)((og0+1)*16 + l15)*128];
      bf16x8 al1 = *(const bf16x8*)&wblo[wo + (long long)((og0+1)*16 + l15)*128];
      #pragma unroll
      for (int ti = 0; ti < 4; ti++){
        if (ti < ntl){
          int px = (tb + ti)*16 + l15;
          int pxe = px < 225 ? px : 224;
          int hp = (pxe/15 + kk/3)*17 + (pxe%15) + (kk%3);
          bf16x8 bh = ldu16x8(&gh[hp*RS + q*8]);
          bf16x8 bl = ldu16x8(&gl[hp*RS + q*8]);
          acc[0][ti] = __builtin_amdgcn_mfma_f32_16x16x32_bf16(ah0, bh, acc[0][ti], 0, 0, 0);
          acc[0][ti] = __builtin_amdgcn_mfma_f32_16x16x32_bf16(ah0, bl, acc[0][ti], 0, 0, 0);
          acc[0][ti] = __builtin_amdgcn_mfma_f32_16x16x32_bf16(al0, bh, acc[0][ti], 0, 0, 0);
          acc[1][ti] = __builtin_amdgcn_mfma_f32_16x16x32_bf16(ah1, bh, acc[1][ti], 0, 0, 0);
          acc[1][ti] = __builtin_amdgcn_mfma_f32_16x16x32_bf16(ah1, bl, acc[1][ti], 0, 0, 0);
          acc[1][ti] = __builtin_amdgcn_mfma_f32_16x16x32_bf16(al1, bh, acc[1][ti], 0, 0, 0);
        }
      }
    }
  }
  #pragma unroll
  for (int ot = 0; ot < 2; ot++){
    #pragma unroll
    for (int ti = 0; ti < 4; ti++){
      if (ti < ntl){
        int px = (tb + ti)*16 + l15;
        if (px < 225){
          #pragma unroll
          for (int r = 0; r < 4; r++){
            int o = (og0 + ot)*16 + q*4 + r;
            float v = eluf(acc[ot][ti][r] + bias[o]);
            out[((long long)b*64 + o)*225 + px] = v;
          }
        }
      }
    }
  }
}

// ---------------- convT2m (64->32, s=2, p=1, 15x15 -> 29x29, +elu) via parity-decomposed bf16 MFMA ----------------
// Output in PARITY-CLASS layout: t2m[b][o][841] = [ee 225 | eo 210 | oe 210 | oo 196].
// RS=44 (16-bank spread) + b64 operand loads, same as convT3m.
__global__ __launch_bounds__(256)
void convt2m_mfma(const float* __restrict__ in, const unsigned short* __restrict__ wbhi,
                  const unsigned short* __restrict__ wblo, const float* __restrict__ bias,
                  float* __restrict__ out)
{
  constexpr int RS = 44;                 // u16 per hp row: 32 ch + 12 pad
  __shared__ __align__(16) unsigned short gh[256*RS];
  __shared__ __align__(16) unsigned short gl[256*RS];
  const int b  = blockIdx.x;
  const int z  = blockIdx.y;
  const int t  = threadIdx.x;
  const int lane = t & 63, wv = t >> 6;
  const int l15 = lane & 15, q = lane >> 4;
  const int g = z*4 + wv;                // global wave id 0..7; tiles g + 8*i, i<7
  f32x4 acc[2][7];
  #pragma unroll
  for (int og = 0; og < 2; og++)
    #pragma unroll
    for (int i = 0; i < 7; i++) acc[og][i] = (f32x4){0.f,0.f,0.f,0.f};
  {
    unsigned* zg = (unsigned*)gh; unsigned* zl = (unsigned*)gl;
    for (int idx = t; idx < 256*RS/2; idx += 256){ zg[idx] = 0u; zl[idx] = 0u; }
  }
  for (int cq = 0; cq < 2; cq++){
    __syncthreads();
    for (int idx = t; idx < 16*225; idx += 256){
      int c2 = idx / 225, px = idx % 225;
      int c = 2*c2;
      const float* ip = in + ((long long)b*64 + cq*32 + c)*225 + px;
      float f0 = ip[0];
      float f1 = ip[225];
      unsigned h0 = bf16r(f0); unsigned l0 = bf16r(f0 - __uint_as_float(h0<<16));
      unsigned h1 = bf16r(f1); unsigned l1 = bf16r(f1 - __uint_as_float(h1<<16));
      int hp = (px/15)*16 + (px%15);
      *(unsigned*)&gh[hp*RS + c] = h0 | (h1<<16);
      *(unsigned*)&gl[hp*RS + c] = l0 | (l1<<16);
    }
    __syncthreads();
    #pragma unroll
    for (int i = 0; i < 7; i++){
      int T = g + i*8;
      int cls, tt;
      if (T < 15){ cls = 0; tt = T; }
      else if (T < 29){ cls = 1; tt = T - 15; }
      else if (T < 43){ cls = 2; tt = T - 29; }
      else { cls = 3; tt = T - 43; }
      int np = (cls == 0) ? 225 : (cls == 3) ? 196 : 210;
      int Wd = (cls == 0 || cls == 2) ? 15 : 14;
      int p = tt*16 + l15;
      int pe = p < np ? p : np - 1;
      int m = pe / Wd, n = pe % Wd;
      int hp0 = m*16 + n;
      int ry = (cls < 2) ? 1 : 2;
      int rx = ((cls & 1) == 0) ? 1 : 2;
      for (int jy = 0; jy < ry; jy++){
        int wky = (cls < 2) ? 1 : (jy == 0 ? 2 : 0);
        int shy = (cls < 2) ? 0 : (jy == 0 ? 0 : 16);
        for (int jx = 0; jx < rx; jx++){
          int wkx = ((cls & 1) == 0) ? 1 : (jx == 0 ? 2 : 0);
          int shx = ((cls & 1) == 0) ? 0 : (jx == 0 ? 0 : 1);
          int kk = wky*3 + wkx;
          int hp = hp0 + shy + shx;
          bf16x8 bh = ldu16x8(&gh[hp*RS + q*8]);
          bf16x8 bl = ldu16x8(&gl[hp*RS + q*8]);
          const long long wo = ((long long)kk*32)*64 + cq*32 + q*8;
          bf16x8 ah0 = *(const bf16x8*)&wbhi[wo + (long long)l15*64];
          bf16x8 al0 = *(const bf16x8*)&wblo[wo + (long long)l15*64];
          bf16x8 ah1 = *(const bf16x8*)&wbhi[wo + (long long)(16 + l15)*64];
          bf16x8 al1 = *(const bf16x8*)&wblo[wo + (long long)(16 + l15)*64];
          acc[0][i] = __builtin_amdgcn_mfma_f32_16x16x32_bf16(ah0, bh, acc[0][i], 0, 0, 0);
          acc[0][i] = __builtin_amdgcn_mfma_f32_16x16x32_bf16(ah0, bl, acc[0][i], 0, 0, 0);
          acc[0][i] = __builtin_amdgcn_mfma_f32_16x16x32_bf16(al0, bh, acc[0][i], 0, 0, 0);
          acc[1][i] = __builtin_amdgcn_mfma_f32_16x16x32_bf16(ah1, bh, acc[1][i], 0, 0, 0);
          acc[1][i] = __builtin_amdgcn_mfma_f32_16x16x32_bf16(ah1, bl, acc[1][i], 0, 0, 0);
          acc[1][i] = __builtin_amdgcn_mfma_f32_16x16x32_bf16(al1, bh, acc[1][i], 0, 0, 0);
        }
      }
    }
  }
  // epilogue: elu(acc + bias) -> class-layout out[b][o][clsOff + p], coalesced
  #pragma unroll
  for (int i = 0; i < 7; i++){
    int T = g + i*8;
    int cls, tt;
    if (T < 15){ cls = 0; tt = T; }
    else if (T < 29){ cls = 1; tt = T - 15; }
    else if (T < 43){ cls = 2; tt = T - 29; }
    else { cls = 3; tt = T - 43; }
    int np = (cls == 0) ? 225 : (cls == 3) ? 196 : 210;
    int clsOff = (cls == 0) ? 0 : (cls == 1) ? 225 : (cls == 2) ? 435 : 645;
    int p = tt*16 + l15;
    if (p < np){
      #pragma unroll
      for (int og = 0; og < 2; og++){
        #pragma unroll
        for (int r = 0; r < 4; r++){
          int o = og*16 + q*4 + r;
          float v = eluf(acc[og][i][r] + bias[o]);
          out[((long long)b*32 + o)*841 + clsOff + p] = v;
        }
      }
    }
  }
}

// ---------------- convT1m (32->2, k=2, s=1, PP=0), block-per-image LDS ----------------
__global__ __launch_bounds__(256)
void convt1m_lds_kernel(const float* __restrict__ in, const float* __restrict__ w,
                        const float* __restrict__ bias, float* __restrict__ out)
{
  __shared__ float simg[32*841];   // 107,648 B
  __shared__ float wl[256];        // w[32][2][2][2]
  const int b = blockIdx.x, t = threadIdx.x;
  for (int i = t; i < 32*841; i += 256) simg[i] = in[(long long)b*32*841 + i];
  if (t < 256) wl[t] = w[t];
  __syncthreads();
  const float* bsrc = simg;
  for (int i = t; i < 1568; i += 256){
    int x = i % 28; int r = i / 28;
    int y = r % 28; int o = r / 28;
    float acc = bias[o];
    #pragma unroll
    for (int ky = 0; ky < 2; ky++){
      int iy = y + ky;                 // PP=0
      int wky = 1 - ky;
      #pragma unroll
      for (int kx = 0; kx < 2; kx++){
        int ix = x + kx;               // PP=0
        int wkx = 1 - kx;
        int cls = (iy & 1)*2 + (ix & 1);
        int Wd  = (ix & 1) ? 14 : 15;
        int off = ((cls == 0) ? 0 : (cls == 1) ? 225 : (cls == 2) ? 435 : 645)
                + (iy >> 1)*Wd + (ix >> 1);
        const float* ip = bsrc + off;
        for (int c = 0; c < 32; c++){
          acc += wl[((c*2 + o)*2 + wky)*2 + wkx] * ip[c*841];
        }
      }
    }
    out[(long long)b*1568 + i] = eluf(acc);
  }
}

// ---------------- bn + elu + 2x2 avgpool (kept for bn3) ----------------
__global__ void bn_elu_pool_kernel(const float* __restrict__ in, const float* __restrict__ g,
                                   const float* __restrict__ bb, const float* __restrict__ sum,
                                   const float* __restrict__ sq, float* __restrict__ out,
                                   int B, int C, int H, int W, float invN)
{
  int Ho = H/2, Wo = W/2;
  int idx = blockIdx.x*256 + threadIdx.x;
  int total = B*C*Ho*Wo;
  if (idx >= total) return;
  int x = idx % Wo; int t = idx / Wo;
  int y = t % Ho;   t /= Ho;
  int c = t % C;    int b = t / C;
  float mean = sum[c]*invN;
  float var  = sq[c]*invN - mean*mean;
  float sc = g[c] * rsqrtf(var + 1e-5f);
  float sh = bb[c] - mean*sc;
  const float* p = in + (long long)(b*C + c)*H*W;
  float acc = 0.f;
  #pragma unroll
  for (int dy = 0; dy < 2; dy++)
    #pragma unroll
    for (int dx = 0; dx < 2; dx++)
      acc += eluf(sc*p[(2*y+dy)*W + (2*x+dx)] + sh);
  out[idx] = acc * 0.25f;
}

// ---------------- bn + elu in place (kept for bn41) ----------------
__global__ void bn_elu_inplace_kernel(float* __restrict__ xio, const float* __restrict__ g,
                                      const float* __restrict__ bb, const float* __restrict__ sum,
                                      const float* __restrict__ sq, int C, int HW, float invN, int total)
{
  int idx = blockIdx.x*256 + threadIdx.x;
  if (idx >= total) return;
  int c = (idx / HW) % C;
  float mean = sum[c]*invN;
  float var  = sq[c]*invN - mean*mean;
  float sc = g[c] * rsqrtf(var + 1e-5f);
  float sh = bb[c] - mean*sc;
  xio[idx] = eluf(sc*xio[idx] + sh);
}

// ---------------- final bicubic warp ----------------
__device__ __forceinline__ float cubicf(float A, float Bv, float C, float D, float t){
  float a = -0.5f*A + 1.5f*Bv - 1.5f*C + 0.5f*D;
  float b =  A - 2.5f*Bv + 2.0f*C - 0.5f*D;
  float c = -0.5f*A + 0.5f*C;
  return ((a*t + b)*t + c)*t + Bv;
}

__global__ void warp_kernel(const float* __restrict__ V, const float* __restrict__ x1,
                            float* __restrict__ out, int B)
{
  int idx = blockIdx.x*256 + threadIdx.x;
  int total = B*784;
  if (idx >= total) return;
  int j = idx % 28; int t = idx / 28;
  int i = t % 28;   int b = t / 28;
  float v0 = V[((long long)b*2 + 0)*784 + j*28 + i];
  float v1 = V[((long long)b*2 + 1)*784 + j*28 + i];
  float gx = (-1.f + 2.f*(float)j/27.f) + v0;
  float gy = (-1.f + 2.f*(float)i/27.f) + v1;
  float ix = (gx + 1.f)*13.5f;
  float iy = (gy + 1.f)*13.5f;
  float x0 = floorf(ix), y0 = floorf(iy);
  float tx = ix - x0, ty = iy - y0;
  const float* img = x1 + (long long)b*2*784;
  float rows[4];
  #pragma unroll
  for (int ky = -1; ky <= 2; ky++){
    int yi = (int)fminf(fmaxf(y0 + (float)ky, 0.f), 27.f);
    float cv[4];
    #pragma unroll
    for (int kx = -1; kx <= 2; kx++){
      int xi = (int)fminf(fmaxf(x0 + (float)kx, 0.f), 27.f);
      cv[kx+1] = img[yi*28 + xi];
    }
    rows[ky+1] = cubicf(cv[0], cv[1], cv[2], cv[3], tx);
  }
  out[idx] = cubicf(rows[0], rows[1], rows[2], rows[3], ty);
}

// ---------------- host ----------------
extern "C" void kernel_launch(void* const* d_in, const int* in_sizes, int n_in,
                              void* d_out, int out_size, void* d_ws, size_t ws_size,
                              hipStream_t stream)
{
  const int B = 256;
  const float* x1      = (const float*)d_in[0];
  const float* conv1_w = (const float*)d_in[9];
  const float* conv1_b = (const float*)d_in[10];
  const float* bn1_g   = (const float*)d_in[11];
  const float* bn1_b   = (const float*)d_in[12];
  const float* dc2_pw  = (const float*)d_in[13];
  const float* dc2_pb  = (const float*)d_in[14];
  const float* dc2_mw  = (const float*)d_in[15];
  const float* dc2_mb  = (const float*)d_in[16];
  const float* dc2_w   = (const float*)d_in[17];
  const float* bn2_g   = (const float*)d_in[18];
  const float* bn2_b   = (const float*)d_in[19];
  const float* conv3_w = (const float*)d_in[20];
  const float* conv3_b = (const float*)d_in[21];
  const float* bn3_g   = (const float*)d_in[22];
  const float* bn3_b   = (const float*)d_in[23];
  const float* dc41_pw = (const float*)d_in[24];
  const float* dc41_pb = (const float*)d_in[25];
  const float* dc41_mw = (const float*)d_in[26];
  const float* dc41_mb = (const float*)d_in[27];
  const float* dc41_w  = (const float*)d_in[28];
  const float* bn41_g  = (const float*)d_in[29];
  const float* bn41_b  = (const float*)d_in[30];
  const float* conv4_w = (const float*)d_in[31];
  const float* conv4_b = (const float*)d_in[32];
  const float* conv4m_w= (const float*)d_in[33];
  const float* conv4m_b= (const float*)d_in[34];
  const float* conv3m_w= (const float*)d_in[35];
  const float* conv3m_b= (const float*)d_in[36];
  const float* conv2m_w= (const float*)d_in[37];
  const float* conv2m_b= (const float*)d_in[38];
  const float* conv1m_w= (const float*)d_in[39];
  const float* conv1m_b= (const float*)d_in[40];

  float* ws = (float*)d_ws;

  // lifetime-packed arena (floats), stats in [0,1024).
  // cpart (conv1 stats partials, 32K floats) aliases p1 start: live [1]->[1.5] only,
  // consumed before conv1_pool writes p1 (stream-ordered). a2b at ws+AB, consumed at [6].
  // t2m (class layout) at AB+1048576: overlapped buffers dead by step [14].
  const long long AB = 1024;
  float* p1   = ws + AB;
  float* cpart= ws + AB;                // 2048*16 floats, [1]->[1.5]
  float* om2  = ws + AB + 3211264;
  float* a2   = ws + AB + 4566016;
  float* a3   = ws + AB + 10988544;
  float* p2   = ws + AB;
  float* om41 = ws + AB + 1605632;
  float* a41  = ws + AB + 1944320;
  float* a4   = ws + AB + 2747136;
  float* t4m  = ws + AB + 2772224;
  float* t3m  = ws + AB + 8310016;
  float* t2m  = ws + AB + 1048576;      // class layout [b][32][841]
  float* t1m  = ws + AB;
  unsigned int* a2b = (unsigned int*)(ws + AB);                     // 4,194,304 u32 (16.8MB)
  unsigned short* wb2f   = (unsigned short*)(ws + AB + 17411072);   // 81920 u16
  unsigned short* wb41f  = wb2f + 81920;                            // 81920 u16
  unsigned short* wb3mhi = (unsigned short*)(ws + AB + 17705984);   // 73728 u16 each
  unsigned short* wb3mlo = wb3mhi + 73728;
  unsigned short* wb3 = (unsigned short*)(ws + AB + 17779712);
  unsigned short* wb2mhi = (unsigned short*)(ws + AB);              // 18432 u16 each, low arena
  unsigned short* wb2mlo = wb2mhi + 18432;

  float* s1  = ws + 0;   float* q1  = ws + 64;
  float* s2  = ws + 128; float* q2  = ws + 256;
  float* s3  = ws + 384; float* q3  = ws + 512;
  float* s41 = ws + 640; float* q41 = ws + 704;

  auto nb = [](long long n){ return (int)((n + 255)/256); };

  hipMemsetAsync(d_ws, 0, 4096, stream);

  // weight pre-transposes / packs
  wconv3_bf16_kernel<<<nb(147456), 256, 0, stream>>>(conv3_w, wb3);
  wdeform_f16_kernel<<<nb(81920), 256, 0, stream>>>(dc2_w,  wb2f,  64, 128);
  wdeform_f16_kernel<<<nb(81920), 256, 0, stream>>>(dc41_w, wb41f, 128, 64);
  wconvt3m_split_kernel<<<nb(73728), 256, 0, stream>>>(conv3m_w, wb3mhi, wb3mlo);

  // [1] conv1 stats partials (no global atomics)
  conv1_stats<<<dim3(B,8), 256, 0, stream>>>(x1, conv1_w, conv1_b, cpart);
  // [1.5] reduce partials -> s1/q1
  conv1_reduce<<<1, 256, 0, stream>>>(cpart, s1, q1);
  // [2] conv1 recompute + bn1 + elu + avgpool -> p1 (LDS-staged coalesced out)
  conv1_pool<<<dim3(B,4), 256, 0, stream>>>(x1, conv1_w, conv1_b, bn1_g, bn1_b, s1, q1, p1);
  // [3] dc2 offsets (18, raw) + mask (9, sigmoid) fused -> om2; y-split x2, stage-once LDS
  offmask_tiled<64,14,14,2><<<dim3(B,2), 256, 0, stream>>>(p1, dc2_pw, dc2_pb, dc2_mw, dc2_mb, om2);
  // [4] deform conv 2 (64->128) -> a2 via fp16 MFMA, fused bn2 stats
  deform_mfma<64,128,14,14,49,4,4,2><<<dim3(B*4), 256, 0, stream>>>(p1, om2, wb2f, a2, s2, q2);
  // [5] bn2 + elu + bf16 pack into padded staging layout -> a2b
  bn2_pack_kernel<<<nb(4194304), 256, 0, stream>>>(a2, bn2_g, bn2_b, s2, q2, a2b);
  // [6] conv3 (128->128) -> a3 via bf16 MFMA, 64-o tile, fused bn3 stats
  conv3_mfma2<<<dim3(B,2), 256, 0, stream>>>((const unsigned short*)a2b, wb3, conv3_b, a3, s3, q3);
  // [7] bn3 + elu + avgpool -> p2
  bn_elu_pool_kernel<<<nb((long long)B*128*49), 256, 0, stream>>>(a3, bn3_g, bn3_b, s3, q3, p2,
                                                                  B, 128, 14, 14, 1.f/50176.f);
  // [8] dc41 offsets + mask fused -> om41; stage-once LDS, no per-channel barriers
  offmask_tiled<128,7,7,1><<<dim3(B,1), 256, 0, stream>>>(p2, dc41_pw, dc41_pb, dc41_mw, dc41_mb, om41);
  // [9] deform conv 41 (128->64) -> a41 via fp16 MFMA, fused bn41 stats
  deform_mfma<128,64,7,7,13,4,1,1><<<dim3(B*4), 256, 0, stream>>>(p2, om41, wb41f, a41, s41, q41);
  // [10] bn41 + elu
  bn_elu_inplace_kernel<<<nb((long long)B*64*49), 256, 0, stream>>>(a41, bn41_g, bn41_b, s41, q41,
                                                                    64, 49, 1.f/12544.f, B*64*49);
  // [10.5] convT2m weight pack into low arena (consumed at [14], before t1m at [15])
  wconvt2m_split_kernel<<<nb(18432), 256, 0, stream>>>(conv2m_w, wb2mhi, wb2mlo);
  // [11] conv4 (64->2, 7x7): block-per-image LDS kernel
  conv4_tiled<<<B, 256, 0, stream>>>(a41, conv4_w, conv4_b, a4);
  // [12] convT4m: 2->128, s=2, p=1, 7->13, parity-decomposed
  convt_s2_tiled<7,7,2,128,false><<<dim3(B,8), 256, 0, stream>>>(a4, conv4m_w, conv4m_b, t4m);
  // [13] convT3m: 128->64, 13->15 via split-precision bf16 MFMA, fused bias+elu -> t3m
  convt3m_mfma<<<dim3(B,2), 256, 0, stream>>>(t4m, wb3mhi, wb3mlo, conv3m_b, t3m);
  // [14] convT2m: 64->32, s=2, p=1, 15->29, +elu via parity-decomposed bf16 MFMA; class-layout out
  convt2m_mfma<<<dim3(B,2), 256, 0, stream>>>(t3m, wb2mhi, wb2mlo, conv2m_b, t2m);
  // [15] convT1m: 32->2, k=2, s=1, PP=0 taps, +elu; block-per-image LDS staging of class-layout t2m
  convt1m_lds_kernel<<<B, 256, 0, stream>>>(t2m, conv1m_w, conv1m_b, t1m);
  // [16] final warp
  warp_kernel<<<nb((long long)B*784), 256, 0, stream>>>(t1m, x1, (float*)d_out, B);
}

// Round 19
// 673.613 us; speedup vs baseline: 1.0047x; 1.0047x over previous
//
#include <hip/hip_runtime.h>
#include <hip/hip_bf16.h>
#include <hip/hip_fp16.h>

__device__ __forceinline__ float eluf(float x){ return x > 0.f ? x : expm1f(x); }

typedef __attribute__((ext_vector_type(8))) short bf16x8;
typedef __attribute__((ext_vector_type(4))) short bf16x4;
typedef __attribute__((ext_vector_type(8))) _Float16 f16x8;
typedef __attribute__((ext_vector_type(4))) float f32x4;

__device__ __forceinline__ unsigned int bf16r(float f){
  unsigned int u = __float_as_uint(f);
  return (u + 0x7FFFu + ((u >> 16) & 1u)) >> 16;   // RNE
}

__device__ __forceinline__ unsigned short f16b(float f){
  __half h = __float2half(f);                       // RNE
  return __half_as_ushort(h);
}

// 8-byte-aligned bf16x8 load as two b64 reads (for LDS rows that are 8B- but not 16B-aligned)
__device__ __forceinline__ bf16x8 ldu16x8(const unsigned short* p){
  bf16x4 a = *(const bf16x4*)p;
  bf16x4 b = *(const bf16x4*)(p + 4);
  return __builtin_shufflevector(a, b, 0,1,2,3,4,5,6,7);
}

// LDS row stride helper
constexpr int pad_stride(int wp){
  int s = (wp + 3) & ~3;
  return (s % 8 == 0) ? s + 4 : s;
}

// ---------------- conv1 pass A: stats partials (no global atomics) ----------------
__global__ __launch_bounds__(256)
void conv1_stats(const float* __restrict__ in, const float* __restrict__ w,
                 const float* __restrict__ bias, float* __restrict__ part)
{
  constexpr int WPL = pad_stride(30);   // 36
  __shared__ __align__(16) float img[2][30*WPL];
  __shared__ float wl[2][8*9];
  __shared__ float sred[8], qred[8];
  const int b = blockIdx.x, gy = blockIdx.y, o0 = gy*8, t = threadIdx.x;
  const int ol = t & 7, y = t >> 3;
  if (t < 8){ sred[t] = 0.f; qred[t] = 0.f; }
  for (int idx = t; idx < 2*30*WPL; idx += 256) ((float*)img)[idx] = 0.f;
  __syncthreads();
  for (int idx = t; idx < 2*784; idx += 256){
    int cl = idx/784, r = idx%784;
    img[cl][(r/28 + 1)*WPL + (r%28) + 1] = in[((long long)b*2)*784 + idx];
  }
  if (t < 144){
    int cl = t/72, r = t%72;
    wl[cl][r] = w[(((long long)(o0 + r/9))*2 + cl)*9 + (r%9)];
  }
  __syncthreads();
  const bool active = (y < 28);
  float acc[28];
  #pragma unroll
  for (int x = 0; x < 28; x++) acc[x] = 0.f;
  if (active){
    for (int cl = 0; cl < 2; cl++){
      #pragma unroll
      for (int ky = 0; ky < 3; ky++){
        const float* row = &img[cl][(y+ky)*WPL];
        float rin[30];
        #pragma unroll
        for (int q = 0; q < 7; q++){
          float4 v = ((const float4*)row)[q];
          rin[4*q+0]=v.x; rin[4*q+1]=v.y; rin[4*q+2]=v.z; rin[4*q+3]=v.w;
        }
        rin[28] = row[28]; rin[29] = row[29];
        #pragma unroll
        for (int kx = 0; kx < 3; kx++){
          float wv = wl[cl][ol*9 + ky*3 + kx];
          #pragma unroll
          for (int x = 0; x < 28; x++) acc[x] += wv * rin[x+kx];
        }
      }
    }
  }
  const int og = o0 + ol;
  float sv = 0.f, qv = 0.f;
  if (active){
    float bv = bias[og];
    #pragma unroll
    for (int x = 0; x < 28; x++){
      float v = acc[x] + bv;
      sv += v; qv += v*v;
    }
  }
  #pragma unroll
  for (int d = 32; d >= 8; d >>= 1){
    sv += __shfl_down(sv, d);
    qv += __shfl_down(qv, d);
  }
  if ((t & 63) < 8){ atomicAdd(&sred[ol], sv); atomicAdd(&qred[ol], qv); }   // LDS atomics (cheap)
  __syncthreads();
  if (t < 8){
    float* pp = part + ((long long)(b*8 + gy))*16;
    pp[t]     = sred[t];
    pp[t + 8] = qred[t];
  }
}

// ---------------- conv1 stats reduce: 2048x16 partials -> s1/q1 (1 block) ----------------
__global__ __launch_bounds__(256)
void conv1_reduce(const float* __restrict__ part, float* __restrict__ sum, float* __restrict__ sq)
{
  __shared__ float ss[256], qq[256];
  const int t = threadIdx.x;
  const int c = t & 63, seg = t >> 6;        // channel c, batch segment seg (4 x 64)
  const int gy = c >> 3, ol = c & 7;
  float sv = 0.f, qv = 0.f;
  for (int b = seg*64; b < seg*64 + 64; b++){
    const float* pp = part + ((long long)(b*8 + gy))*16;
    sv += pp[ol];
    qv += pp[ol + 8];
  }
  ss[t] = sv; qq[t] = qv;
  __syncthreads();
  if (t < 64){
    sum[c] = ss[t] + ss[t+64] + ss[t+128] + ss[t+192];
    sq[c]  = qq[t] + qq[t+64] + qq[t+128] + qq[t+192];
  }
}

// ---------------- conv1 pass B: recompute conv + bn1 + elu + avgpool -> p1 (LDS-staged coalesced out) ----------------
__global__ __launch_bounds__(256)
void conv1_pool(const float* __restrict__ in, const float* __restrict__ w,
                const float* __restrict__ bias, const float* __restrict__ g,
                const float* __restrict__ bb, const float* __restrict__ sum,
                const float* __restrict__ sq, float* __restrict__ out)
{
  constexpr int WPL = pad_stride(30);   // 36
  constexpr int PST = 197;              // pout row stride (197 mod 32 = 5 -> bank-spread)
  __shared__ __align__(16) float img[2][30*WPL];
  __shared__ float wl[2][16*9];
  __shared__ float pout[16*PST];
  const int b = blockIdx.x, o0 = blockIdx.y*16, t = threadIdx.x;
  const int ol = t & 15, yp = t >> 4;
  for (int idx = t; idx < 2*30*WPL; idx += 256) ((float*)img)[idx] = 0.f;
  __syncthreads();
  for (int idx = t; idx < 2*784; idx += 256){
    int cl = idx/784, r = idx%784;
    img[cl][(r/28 + 1)*WPL + (r%28) + 1] = in[((long long)b*2)*784 + idx];
  }
  for (int idx = t; idx < 288; idx += 256){
    int cl = idx/144, r = idx%144;
    wl[cl][r] = w[(((long long)(o0 + r/9))*2 + cl)*9 + (r%9)];
  }
  __syncthreads();
  if (yp < 14){
    float accA[28], accB[28];
    #pragma unroll
    for (int x = 0; x < 28; x++){ accA[x] = 0.f; accB[x] = 0.f; }
    for (int cl = 0; cl < 2; cl++){
      #pragma unroll
      for (int ky = 0; ky < 3; ky++){
        const float* rowA = &img[cl][(2*yp+ky)*WPL];
        const float* rowB = rowA + WPL;
        float ra[30], rb[30];
        #pragma unroll
        for (int q = 0; q < 7; q++){
          float4 va = ((const float4*)rowA)[q];
          ra[4*q+0]=va.x; ra[4*q+1]=va.y; ra[4*q+2]=va.z; ra[4*q+3]=va.w;
          float4 vb = ((const float4*)rowB)[q];
          rb[4*q+0]=vb.x; rb[4*q+1]=vb.y; rb[4*q+2]=vb.z; rb[4*q+3]=vb.w;
        }
        ra[28]=rowA[28]; ra[29]=rowA[29];
        rb[28]=rowB[28]; rb[29]=rowB[29];
        #pragma unroll
        for (int kx = 0; kx < 3; kx++){
          float wv = wl[cl][ol*9 + ky*3 + kx];
          #pragma unroll
          for (int x = 0; x < 28; x++){
            accA[x] += wv * ra[x+kx];
            accB[x] += wv * rb[x+kx];
          }
        }
      }
    }
    const int og = o0 + ol;
    const float bv = bias[og];
    const float invN = 1.f/200704.f;
    float mean = sum[og]*invN;
    float var  = sq[og]*invN - mean*mean;
    float sc = g[og] * rsqrtf(var + 1e-5f);
    float sh = bb[og] - mean*sc;
    float* po = &pout[ol*PST + yp*14];
    #pragma unroll
    for (int xp = 0; xp < 14; xp++){
      float acc = eluf(sc*(accA[2*xp]   + bv) + sh);
      acc      += eluf(sc*(accA[2*xp+1] + bv) + sh);
      acc      += eluf(sc*(accB[2*xp]   + bv) + sh);
      acc      += eluf(sc*(accB[2*xp+1] + bv) + sh);
      po[xp] = acc * 0.25f;
    }
  }
  __syncthreads();
  // coalesced block-wide store: 3136 contiguous floats at p1[b][o0..o0+16][..]
  float* gbase = out + ((long long)b*64 + o0)*196;
  for (int idx = t; idx < 3136; idx += 256)
    gbase[idx] = pout[(idx/196)*PST + idx%196];
}

// ---------------- fused offsets(18, raw) + mask(9, sigmoid) 3x3 pad-1 conv ----------------
template<int CIN,int H,int W,int NZ>
__global__ __launch_bounds__(256)
void offmask_tiled(const float* __restrict__ in, const float* __restrict__ pw,
                   const float* __restrict__ pb, const float* __restrict__ mw,
                   const float* __restrict__ mb, float* __restrict__ om)
{
  constexpr int Hz  = H/NZ;
  constexpr int HP  = Hz + 2;
  constexpr int WP  = W + 2;
  constexpr int WPL = pad_stride(WP);
  __shared__ __align__(16) float img[CIN*HP*WPL];
  const int b = blockIdx.x;
  const int z = blockIdx.y;
  const int t = threadIdx.x;
  for (int i = t; i < CIN*HP*WPL; i += 256) img[i] = 0.f;
  __syncthreads();
  const int base = z*Hz - 1;                       // padded row 0 <-> global row `base`
  const int gy0  = (base < 0) ? 0 : base;
  const int gy1  = (z*Hz + Hz + 1 > H) ? H : z*Hz + Hz + 1;
  const int nrows = gy1 - gy0;
  for (int i = t; i < CIN*nrows*W; i += 256){
    int x = i % W; int r = i / W;
    int row = r % nrows; int c = r / nrows;
    int gy = gy0 + row;
    img[(c*HP + (gy - base))*WPL + (x+1)] = in[((long long)b*CIN + c)*(H*W) + gy*W + x];
  }
  __syncthreads();
  const int o  = t & 31;
  const int yl = t >> 5;
  const int y  = z*Hz + yl;
  if (o < 27 && yl < Hz && y < H){
    float acc[W];
    #pragma unroll
    for (int x = 0; x < W; x++) acc[x] = 0.f;
    const float* wsrc = (o < 18) ? (pw + (long long)o*CIN*9) : (mw + (long long)(o-18)*CIN*9);
    for (int c = 0; c < CIN; c++){
      const float* wc = wsrc + c*9;
      float4 wa = *(const float4*)wc;
      float4 wbv = *(const float4*)(wc+4);
      float w8 = wc[8];
      const float* rm = &img[(c*HP + yl  )*WPL];
      const float* r0 = &img[(c*HP + yl+1)*WPL];
      const float* rp = &img[(c*HP + yl+2)*WPL];
      #pragma unroll
      for (int x = 0; x < W; x++){
        acc[x] += wa.x*rm[x] + wa.y*rm[x+1] + wa.z*rm[x+2]
                + wa.w*r0[x] + wbv.x*r0[x+1] + wbv.y*r0[x+2]
                + wbv.z*rp[x] + wbv.w*rp[x+1] + w8*rp[x+2];
      }
    }
    float bv = (o < 18) ? pb[o] : mb[o-18];
    float* po = om + (((long long)b*27 + o)*H + y)*W;
    #pragma unroll
    for (int x = 0; x < W; x++){
      float v = acc[x] + bv;
      if (o >= 18) v = 1.f/(1.f + expf(-v));
      po[x] = v;
    }
  }
}

// ---------------- conv4 (64->2, 7x7, pad 1): block-per-image LDS kernel ----------------
__global__ __launch_bounds__(256)
void conv4_tiled(const float* __restrict__ in, const float* __restrict__ w,
                 const float* __restrict__ bias, float* __restrict__ out)
{
  __shared__ __align__(16) float img[64*9*12];   // padded [c][9][12], 27.6KB
  __shared__ float wl[1152];                     // w[2][64][9], 4.6KB
  const int b = blockIdx.x, t = threadIdx.x;
  for (int i = t; i < 64*108; i += 256) img[i] = 0.f;
  __syncthreads();
  for (int i = t; i < 64*49; i += 256){
    int px = i % 49, c = i / 49;
    img[(c*9 + px/7 + 1)*12 + (px%7) + 1] = in[((long long)b*64 + c)*49 + px];
  }
  for (int i = t; i < 1152; i += 256) wl[i] = w[i];
  __syncthreads();
  const int o  = t >> 7;
  const int px = t & 127;
  if (px < 49){
    int y = px/7, x = px%7;
    float acc = bias[o];
    const float* wo = &wl[o*576];
    for (int c = 0; c < 64; c++){
      const float* rm = &img[(c*9 + y)*12 + x];
      const float* r0 = rm + 12;
      const float* rp = rm + 24;
      const float* wc = wo + c*9;
      acc += wc[0]*rm[0]+wc[1]*rm[1]+wc[2]*rm[2]
           + wc[3]*r0[0]+wc[4]*r0[1]+wc[5]*r0[2]
           + wc[6]*rp[0]+wc[7]*rp[1]+wc[8]*rp[2];
    }
    out[((long long)b*2 + o)*49 + px] = acc;
  }
}

// ---------------- conv3 weights -> bf16 wb[kk][o][c] ----------------
__global__ void wconv3_bf16_kernel(const float* __restrict__ w, unsigned short* __restrict__ wb)
{
  int idx = blockIdx.x*256 + threadIdx.x;
  if (idx >= 147456) return;
  int kk = idx >> 14;
  int r  = idx & 16383;
  int o  = r >> 7, c = r & 127;
  wb[idx] = (unsigned short)bf16r(w[((long long)o*128 + c)*9 + kk]);
}

// ---------------- bn2 + elu + bf16 pack into padded [b][ch][hp=256][64] layout ----------------
__global__ void bn2_pack_kernel(const float* __restrict__ a2, const float* __restrict__ g,
                                const float* __restrict__ bb, const float* __restrict__ sum,
                                const float* __restrict__ sq, unsigned int* __restrict__ a2b)
{
  int idx = blockIdx.x*256 + threadIdx.x;
  if (idx >= 4194304) return;                 // 256 b x 2 ch x 256 hp x 32 u32
  int c2 = idx & 31; int r = idx >> 5;
  int hp = r & 255; r >>= 8;
  int ch = r & 1; int b = r >> 1;
  int row = hp >> 4, col = hp & 15;
  unsigned val = 0u;
  if (row >= 1 && row <= 14 && col >= 1 && col <= 14){
    int px = (row-1)*14 + (col-1);
    int c = ch*64 + 2*c2;
    const float invN = 1.f/50176.f;
    float m0 = sum[c]*invN,     m1 = sum[c+1]*invN;
    float v0 = sq[c]*invN - m0*m0, v1 = sq[c+1]*invN - m1*m1;
    float sc0 = g[c]*rsqrtf(v0 + 1e-5f), sc1 = g[c+1]*rsqrtf(v1 + 1e-5f);
    float sh0 = bb[c] - m0*sc0, sh1 = bb[c+1] - m1*sc1;
    float x0 = a2[((long long)b*128 + c)*196 + px];
    float x1 = a2[((long long)b*128 + c + 1)*196 + px];
    float e0 = eluf(sc0*x0 + sh0), e1 = eluf(sc1*x1 + sh1);
    val = bf16r(e0) | (bf16r(e1) << 16);
  }
  a2b[idx] = val;
}

// ---------------- conv3 via bf16 MFMA, 64-o tile, pre-packed bf16 input ----------------
__global__ __launch_bounds__(256)
void conv3_mfma2(const unsigned short* __restrict__ a2b, const unsigned short* __restrict__ wb,
                 const float* __restrict__ bias, float* __restrict__ out,
                 float* __restrict__ sum, float* __restrict__ sq)
{
  constexpr int RS = 72;                       // u16 per hp row: 64 ch + 8 pad
  __shared__ __align__(16) unsigned short img[256*RS];
  __shared__ float sred[64], qred[64];
  const int b  = blockIdx.x;
  const int o0 = blockIdx.y * 64;
  const int t  = threadIdx.x;
  const int lane = t & 63, wv = t >> 6;
  const int l15 = lane & 15, q = lane >> 4;
  const int ntile = (wv == 0) ? 4 : 3;
  if (t < 64){ sred[t] = 0.f; qred[t] = 0.f; }
  int rbase[4];
  #pragma unroll
  for (int ti = 0; ti < 4; ti++){
    int px = (wv + ti*4)*16 + l15;
    int pxe = px < 196 ? px : 195;
    rbase[ti] = (pxe/14)*16 + (pxe%14);
  }
  f32x4 acc[4][4];
  #pragma unroll
  for (int og = 0; og < 4; og++)
    #pragma unroll
    for (int ti = 0; ti < 4; ti++) acc[og][ti] = (f32x4){0.f,0.f,0.f,0.f};
  for (int ch = 0; ch < 2; ch++){
    __syncthreads();                            // prev MFMA reads done
    const unsigned short* src = a2b + ((long long)(b*2 + ch))*16384;
    for (int it = t; it < 2048; it += 256){     // 2048 x 16B chunks (256 rows x 128B)
      int r = it >> 3, j = it & 7;
      uint4 v = *(const uint4*)(src + r*64 + j*8);
      *(uint4*)&img[r*RS + j*8] = v;
    }
    __syncthreads();
    #pragma unroll
    for (int kk = 0; kk < 9; kk++){
      int dh = (kk/3)*16 + (kk%3);
      #pragma unroll
      for (int ks = 0; ks < 2; ks++){
        bf16x8 bf[4];
        #pragma unroll
        for (int ti = 0; ti < 4; ti++)
          if (ti < ntile)
            bf[ti] = *(const bf16x8*)&img[(rbase[ti]+dh)*RS + ks*32 + q*8];
        #pragma unroll
        for (int og = 0; og < 4; og++){
          const unsigned short* wp = wb + (((long long)kk*128 + o0 + og*16 + l15)*128 + ch*64 + ks*32 + q*8);
          bf16x8 af = *(const bf16x8*)wp;
          #pragma unroll
          for (int ti = 0; ti < 4; ti++)
            if (ti < ntile)
              acc[og][ti] = __builtin_amdgcn_mfma_f32_16x16x32_bf16(af, bf[ti], acc[og][ti], 0, 0, 0);
        }
      }
    }
  }
  // epilogue: out = acc + bias (raw, bn3 applied later) + fused bn3 stats
  float svl[4][4], qvl[4][4];
  #pragma unroll
  for (int og = 0; og < 4; og++)
    #pragma unroll
    for (int r = 0; r < 4; r++){ svl[og][r] = 0.f; qvl[og][r] = 0.f; }
  #pragma unroll
  for (int og = 0; og < 4; og++){
    #pragma unroll
    for (int ti = 0; ti < 4; ti++){
      if (ti < ntile){
        int px = (wv + ti*4)*16 + l15;
        if (px < 196){
          #pragma unroll
          for (int r = 0; r < 4; r++){
            int o = o0 + og*16 + q*4 + r;
            float v = acc[og][ti][r] + bias[o];
            out[((long long)b*128 + o)*196 + px] = v;
            svl[og][r] += v; qvl[og][r] += v*v;
          }
        }
      }
    }
  }
  #pragma unroll
  for (int og = 0; og < 4; og++)
    #pragma unroll
    for (int r = 0; r < 4; r++)
      #pragma unroll
      for (int m = 1; m < 16; m <<= 1){
        svl[og][r] += __shfl_xor(svl[og][r], m);
        qvl[og][r] += __shfl_xor(qvl[og][r], m);
      }
  if (l15 == 0){
    #pragma unroll
    for (int og = 0; og < 4; og++)
      #pragma unroll
      for (int r = 0; r < 4; r++){
        atomicAdd(&sred[og*16 + q*4 + r], svl[og][r]);
        atomicAdd(&qred[og*16 + q*4 + r], qvl[og][r]);
      }
  }
  __syncthreads();
  if (t < 64){ atomicAdd(&sum[o0 + t], sred[t]); atomicAdd(&sq[o0 + t], qred[t]); }
}

// ---------------- stride-2 transpose conv, parity-decomposed (kept for convT4m) ----------------
template<int HIN,int WIN,int CIN,int COUT,bool DO_ELU>
__global__ __launch_bounds__(256)
void convt_s2_tiled(const float* __restrict__ in, const float* __restrict__ w,
                    const float* __restrict__ bias, float* __restrict__ out)
{
  constexpr int HOUT = 2*HIN - 1, WOUT = 2*WIN - 1;
  constexpr int RS = 20;
  __shared__ __align__(16) float img[17*RS];
  __shared__ float wl[16][10];
  const int b  = blockIdx.x;
  const int o0 = blockIdx.y * 16;
  const int t  = threadIdx.x;
  const int ol = t & 15, yb = t >> 4;
  for (int idx = t; idx < 17*RS; idx += 256) img[idx] = 0.f;
  float accA[WOUT], accB[WOUT];
  #pragma unroll
  for (int x = 0; x < WOUT; x++){ accA[x] = 0.f; accB[x] = 0.f; }
  for (int c = 0; c < CIN; c++){
    __syncthreads();
    for (int idx = t; idx < HIN*WIN; idx += 256)
      img[(idx/WIN)*RS + idx%WIN] = in[((long long)b*CIN + c)*HIN*WIN + idx];
    if (t < 144)
      wl[t/9][t%9] = w[(((long long)c*COUT + o0 + t/9)*3 + (t%9)/3)*3 + (t%9)%3];
    __syncthreads();
    float ru[16], rd[16];
    #pragma unroll
    for (int q = 0; q < 4; q++){
      float4 va = ((const float4*)&img[yb*RS])[q];
      ru[4*q+0]=va.x; ru[4*q+1]=va.y; ru[4*q+2]=va.z; ru[4*q+3]=va.w;
      float4 vb = ((const float4*)&img[(yb+1)*RS])[q];
      rd[4*q+0]=vb.x; rd[4*q+1]=vb.y; rd[4*q+2]=vb.z; rd[4*q+3]=vb.w;
    }
    float w00=wl[ol][0], w01=wl[ol][1], w02=wl[ol][2];
    float w10=wl[ol][3], w11=wl[ol][4], w12=wl[ol][5];
    float w20=wl[ol][6], w21=wl[ol][7], w22=wl[ol][8];
    #pragma unroll
    for (int v = 0; v < WIN; v++){
      accA[2*v] += w11*ru[v];
      accB[2*v] += w21*ru[v] + w01*rd[v];
    }
    #pragma unroll
    for (int v = 0; v < WIN-1; v++){
      accA[2*v+1] += w12*ru[v] + w10*ru[v+1];
      accB[2*v+1] += w22*ru[v] + w20*ru[v+1] + w02*rd[v] + w00*rd[v+1];
    }
  }
  const int og = o0 + ol;
  const float bv = bias[og];
  const int yA = 2*yb, yB = 2*yb + 1;
  if (yA < HOUT){
    float* po = out + (((long long)b*COUT + og)*HOUT + yA)*WOUT;
    #pragma unroll
    for (int x = 0; x < WOUT; x++){ float v = accA[x] + bv; po[x] = DO_ELU ? eluf(v) : v; }
  }
  if (yB < HOUT){
    float* po = out + (((long long)b*COUT + og)*HOUT + yB)*WOUT;
    #pragma unroll
    for (int x = 0; x < WOUT; x++){ float v = accB[x] + bv; po[x] = DO_ELU ? eluf(v) : v; }
  }
}

// ---------------- deform weights -> fp16, [ch][o][160] (K = kk*16 + p; pad 144..159 = 0) ----------------
// Position p within a 16-channel chunk holds channel (p>>3) + 2*(p&7)  (2x8 transpose),
// matching deform_mfma's v5 8-channel plane-per-lane gather order.
__global__ void wdeform_f16_kernel(const float* __restrict__ w, unsigned short* __restrict__ wf,
                                   int CIN, int COUT)
{
  int n = (CIN/16)*COUT*160;
  int idx = blockIdx.x*256 + threadIdx.x;
  if (idx >= n) return;
  int ch = idx / (COUT*160);
  int r  = idx % (COUT*160);
  int o  = r / 160, k = r % 160;
  unsigned short h = 0;
  if (k < 144){
    int kk = k >> 4, cp = k & 15;
    int cl = (cp >> 3) + 2*(cp & 7);          // position -> channel (matches writer)
    h = f16b(w[((long long)o*CIN + ch*16 + cl)*9 + kk]);
  }
  wf[idx] = h;
}

// ---------------- convT3m flipped weights -> hi/lo bf16, [kk][o=64][c=128] ----------------
__global__ void wconvt3m_split_kernel(const float* __restrict__ w, unsigned short* __restrict__ whi,
                                      unsigned short* __restrict__ wlo)
{
  int idx = blockIdx.x*256 + threadIdx.x;
  if (idx >= 73728) return;
  int kk = idx / 8192;
  int r  = idx % 8192;
  int o  = r >> 7, c = r & 127;
  int ky = kk/3, kx = kk%3;
  float v = w[(((long long)c*64 + o)*3 + (2-ky))*3 + (2-kx)];
  unsigned hu = bf16r(v);
  float res = v - __uint_as_float(hu << 16);
  whi[idx] = (unsigned short)hu;
  wlo[idx] = (unsigned short)bf16r(res);
}

// ---------------- convT2m weights -> hi/lo bf16, [kk=wky*3+wkx][o=32][c=64] ----------------
__global__ void wconvt2m_split_kernel(const float* __restrict__ w, unsigned short* __restrict__ whi,
                                      unsigned short* __restrict__ wlo)
{
  int idx = blockIdx.x*256 + threadIdx.x;
  if (idx >= 18432) return;
  int kk = idx / 2048;
  int r  = idx % 2048;
  int o  = r >> 6, c = r & 63;
  float v = w[((long long)c*32 + o)*9 + kk];
  unsigned hu = bf16r(v);
  float res = v - __uint_as_float(hu << 16);
  whi[idx] = (unsigned short)hu;
  wlo[idx] = (unsigned short)bf16r(res);
}

// ---------------- deformable conv via fp16 MFMA (single-product; ~2^-11 rel) ----------------
// v5: 8-channel gather -- lane c2 in {0,1} owns planes {c2, c2+2, ..., c2+14} (stride 2HW;
// group bank bases {0,4} dc2 / {0,17} dc41 -> distinct). Halves gather iterations and
// kwv/kidx re-reads vs v4; Gf write is one 16B store. Weights permuted to match
// (wdeform_f16_kernel: cl = (p>>3) + 2*(p&7)). Direct float4 global->LDS staging.
template<int CIN,int COUT,int H,int W,int PXT,int NT,int NPT,int OTW>
__global__ __launch_bounds__(256)
void deform_mfma(const float* __restrict__ x, const float* __restrict__ om,
                 const unsigned short* __restrict__ wf,
                 float* __restrict__ out, float* __restrict__ sum, float* __restrict__ sq)
{
  constexpr int HW  = H*W;
  constexpr int CC  = 16;          // channels per chunk
  constexpr int NCH = CIN/CC;
  constexpr int GS  = 168;         // u16 per G row: 144 K + 16 zero-pad + 8 bank-pad
  constexpr int KP  = 160;         // padded K per chunk (5 MFMA K-steps of 32)
  __shared__ __align__(16) float simg[CC*HW];
  __shared__ __align__(16) unsigned short Gf[PXT*GS];
  __shared__ __align__(16) float kwv[PXT*9*4];     // aliased as sred/qred in epilogue
  __shared__ __align__(4)  unsigned char kidx[PXT*9*4];
  const int tile = blockIdx.x % NT;
  const int b    = blockIdx.x / NT;
  const int t    = threadIdx.x;
  const int lane = t & 63, wv = t >> 6;
  const int l15  = lane & 15, q = lane >> 4;
  const int Hp = H + 2, Wp = W + 2;
  for (int idx = t; idx < PXT*16; idx += 256){
    int px = idx >> 4, k = 144 + (idx & 15);
    Gf[px*GS + k] = 0;
  }
  for (int it = t; it < PXT*9; it += 256){
    int px = it / 9, kk = it % 9;
    int p = tile*PXT + px;
    float w0=0.f,w1=0.f,w2=0.f,w3=0.f;
    int i0=0,i1=0,i2=0,i3=0;
    if (p < HW){
      int i = p / W, j = p % W;
      long long base = ((long long)b*27)*HW + p;
      float offx = om[base + (long long)kk*HW];
      float offy = om[base + (long long)(9+kk)*HW];
      float mk   = om[base + (long long)(18+kk)*HW];
      float pnx = (float)(kk/3) - 1.f;
      float pny = (float)(kk%3) - 1.f;
      float px_ = fminf(fmaxf((float)(i+1) + pnx + offx, 0.f), (float)(Hp-1));
      float py_ = fminf(fmaxf((float)(j+1) + pny + offy, 0.f), (float)(Wp-1));
      float fx = floorf(px_), fy = floorf(py_);
      float x0 = fmaxf(fx, 0.f), y0 = fmaxf(fy, 0.f);
      float x1c = fminf(fx + 1.f, (float)(Hp-1));
      float y1c = fminf(fy + 1.f, (float)(Wp-1));
      float glt = (1.f + (x0 - px_)) * (1.f + (y0 - py_));
      float grb = (1.f - (x1c - px_)) * (1.f - (y1c - py_));
      float glb = (1.f + (x0 - px_)) * (1.f - (y1c - py_));
      float grt = (1.f - (x1c - px_)) * (1.f + (y0 - py_));
      int ax0=(int)x0, ay0=(int)y0, ax1=(int)x1c, ay1=(int)y1c;
      if (ax0>=1 && ax0<=H && ay0>=1 && ay0<=W){ w0 = glt*mk; i0 = (ax0-1)*W + (ay0-1); }
      if (ax1>=1 && ax1<=H && ay1>=1 && ay1<=W){ w1 = grb*mk; i1 = (ax1-1)*W + (ay1-1); }
      if (ax0>=1 && ax0<=H && ay1>=1 && ay1<=W){ w2 = glb*mk; i2 = (ax0-1)*W + (ay1-1); }
      if (ax1>=1 && ax1<=H && ay0>=1 && ay0<=W){ w3 = grt*mk; i3 = (ax1-1)*W + (ay0-1); }
    }
    int b4 = it*4;
    kwv[b4+0]=w0; kwv[b4+1]=w1; kwv[b4+2]=w2; kwv[b4+3]=w3;
    kidx[b4+0]=(unsigned char)i0; kidx[b4+1]=(unsigned char)i1;
    kidx[b4+2]=(unsigned char)i2; kidx[b4+3]=(unsigned char)i3;
  }
  int grow[NPT];
  #pragma unroll
  for (int pt = 0; pt < NPT; pt++){
    int p = pt*16 + l15; if (p > PXT-1) p = PXT-1;
    grow[pt] = p*GS;
  }
  f32x4 acc[OTW][NPT];
  #pragma unroll
  for (int ot = 0; ot < OTW; ot++)
    #pragma unroll
    for (int pt = 0; pt < NPT; pt++) acc[ot][pt] = (f32x4){0.f,0.f,0.f,0.f};

  for (int ch = 0; ch < NCH; ch++){
    __syncthreads();
    // vectorized chunk staging: 16 contiguous channel planes, 16B-aligned
    {
      const float4* src = (const float4*)&x[((long long)b*CIN + ch*CC)*HW];
      for (int idx = t; idx < (CC*HW)/4; idx += 256)
        ((float4*)simg)[idx] = src[idx];
    }
    __syncthreads();
    // 8-channel gather iterations; lane c2 owns planes {c2, c2+2, ..., c2+14}
    for (int it = t; it < PXT*9*2; it += 256){
      int c2 = it & 1; int r = it >> 1;
      int kk = r % 9, px = r / 9;
      int b4 = (px*9 + kk)*4;
      float4 wv4 = *(const float4*)&kwv[b4];
      uchar4 id4 = *(const uchar4*)&kidx[b4];
      const float* pl = &simg[c2*HW];
      unsigned long long uo0 = 0ull, uo1 = 0ull;
      #pragma unroll
      for (int u = 0; u < 4; u++){
        const float* im = pl + u*(2*HW);   // channel c2 + 2u
        float v = wv4.x*im[id4.x] + wv4.y*im[id4.y] + wv4.z*im[id4.z] + wv4.w*im[id4.w];
        uo0 |= (unsigned long long)f16b(v) << (16*u);
      }
      #pragma unroll
      for (int u = 4; u < 8; u++){
        const float* im = pl + u*(2*HW);   // channel c2 + 2u
        float v = wv4.x*im[id4.x] + wv4.y*im[id4.y] + wv4.z*im[id4.z] + wv4.w*im[id4.w];
        uo1 |= (unsigned long long)f16b(v) << (16*(u-4));
      }
      ulonglong2 st; st.x = uo0; st.y = uo1;
      *(ulonglong2*)&Gf[px*GS + kk*16 + 8*c2] = st;   // positions 8c2+u <-> channels c2+2u (weights permuted)
    }
    __syncthreads();
    const unsigned short* wh = wf + (long long)ch*COUT*KP;
    #pragma unroll
    for (int st = 0; st < 5; st++){
      f16x8 bh[NPT];
      #pragma unroll
      for (int pt = 0; pt < NPT; pt++)
        bh[pt] = *(const f16x8*)&Gf[grow[pt] + st*32 + q*8];
      #pragma unroll
      for (int ot = 0; ot < OTW; ot++){
        int o = (wv*OTW + ot)*16 + l15;
        f16x8 ah = *(const f16x8*)&wh[o*KP + st*32 + q*8];
        #pragma unroll
        for (int pt = 0; pt < NPT; pt++)
          acc[ot][pt] = __builtin_amdgcn_mfma_f32_16x16x32_f16(ah, bh[pt], acc[ot][pt], 0, 0, 0);
      }
    }
  }
  float* sred = kwv;
  float* qred = kwv + COUT;
  float sv[OTW][4], qv[OTW][4];
  #pragma unroll
  for (int ot = 0; ot < OTW; ot++)
    #pragma unroll
    for (int r = 0; r < 4; r++){ sv[ot][r] = 0.f; qv[ot][r] = 0.f; }
  #pragma unroll
  for (int ot = 0; ot < OTW; ot++){
    #pragma unroll
    for (int pt = 0; pt < NPT; pt++){
      int p = pt*16 + l15;
      int gp = tile*PXT + p;
      bool ok = (p < PXT) && (gp < HW);
      #pragma unroll
      for (int r = 0; r < 4; r++){
        if (ok){
          int o = (wv*OTW + ot)*16 + q*4 + r;
          float v = acc[ot][pt][r];
          out[((long long)b*COUT + o)*HW + gp] = v;
          sv[ot][r] += v; qv[ot][r] += v*v;
        }
      }
    }
  }
  #pragma unroll
  for (int ot = 0; ot < OTW; ot++)
    #pragma unroll
    for (int r = 0; r < 4; r++)
      #pragma unroll
      for (int m = 1; m < 16; m <<= 1){
        sv[ot][r] += __shfl_xor(sv[ot][r], m);
        qv[ot][r] += __shfl_xor(qv[ot][r], m);
      }
  __syncthreads();
  if (t < COUT){ sred[t] = 0.f; qred[t] = 0.f; }
  __syncthreads();
  if (l15 == 0){
    #pragma unroll
    for (int ot = 0; ot < OTW; ot++)
      #pragma unroll
      for (int r = 0; r < 4; r++){
        int o = (wv*OTW + ot)*16 + q*4 + r;
        atomicAdd(&sred[o], sv[ot][r]);
        atomicAdd(&qred[o], qv[ot][r]);
      }
  }
  __syncthreads();
  if (t < COUT){ atomicAdd(&sum[t], sred[t]); atomicAdd(&sq[t], qred[t]); }
}

// ---------------- convT3m (128->64, 13x13 -> 15x15 pad-2 flipped conv) via bf16 MFMA hi/lo ----------------
// RS=44: row stride 22 words, gcd(22,32)=2 -> 16 distinct banks per 16-lane group.
// Rows 8B-aligned only -> operand loads via two b64 reads (ldu16x8).
__global__ __launch_bounds__(256)
void convt3m_mfma(const float* __restrict__ in, const unsigned short* __restrict__ wbhi,
                  const unsigned short* __restrict__ wblo, const float* __restrict__ bias,
                  float* __restrict__ out)
{
  constexpr int RS = 44;                 // u16 per hp row: 32 ch + 12 pad
  __shared__ __align__(16) unsigned short gh[289*RS];
  __shared__ __align__(16) unsigned short gl[289*RS];
  const int b  = blockIdx.x;
  const int zt = blockIdx.y;             // 0: tiles 0..7, 1: tiles 8..14
  const int t  = threadIdx.x;
  const int lane = t & 63, wv = t >> 6;
  const int l15 = lane & 15, q = lane >> 4;
  const int og0 = (wv & 1)*2;            // o-groups og0, og0+1
  const int tb  = zt*8 + (wv >> 1)*4;    // first tile for this wave
  const int ntl = (zt == 0) ? 4 : ((wv >> 1) ? 3 : 4);
  f32x4 acc[2][4];
  #pragma unroll
  for (int ot = 0; ot < 2; ot++)
    #pragma unroll
    for (int ti = 0; ti < 4; ti++) acc[ot][ti] = (f32x4){0.f,0.f,0.f,0.f};
  {
    unsigned* zg = (unsigned*)gh; unsigned* zl = (unsigned*)gl;
    for (int idx = t; idx < 289*RS/2; idx += 256){ zg[idx] = 0u; zl[idx] = 0u; }
  }
  for (int cq = 0; cq < 4; cq++){
    __syncthreads();
    for (int idx = t; idx < 16*169; idx += 256){
      int c2 = idx / 169, px = idx % 169;
      int c = 2*c2;
      const float* ip = in + ((long long)b*128 + cq*32 + c)*169 + px;
      float f0 = ip[0];
      float f1 = ip[169];
      unsigned h0 = bf16r(f0); unsigned l0 = bf16r(f0 - __uint_as_float(h0<<16));
      unsigned h1 = bf16r(f1); unsigned l1 = bf16r(f1 - __uint_as_float(h1<<16));
      int hp = (px/13 + 2)*17 + (px%13) + 2;
      *(unsigned*)&gh[hp*RS + c] = h0 | (h1<<16);
      *(unsigned*)&gl[hp*RS + c] = l0 | (l1<<16);
    }
    __syncthreads();
    #pragma unroll
    for (int kk = 0; kk < 9; kk++){
      const long long wo = ((long long)kk*64)*128 + (long long)cq*32 + q*8;
      bf16x8 ah0 = *(const bf16x8*)&wbhi[wo + (long long)(og0*16 + l15)*128];
      bf16x8 al0 = *(const bf16x8*)&wblo[wo + (long long)(og0*16 + l15)*128];
      bf16x8 ah1 = *(const bf16x8*)&wbhi[wo + (long long)((og0+1)*16 + l15)*128];
      bf16x8 al1 = *(const bf16x8*)&wblo[wo + (long long)((og0+1)*16 + l15)*128];
      #pragma unroll
      for (int ti = 0; ti < 4; ti++){
        if (ti < ntl){
          int px = (tb + ti)*16 + l15;
          int pxe = px < 225 ? px : 224;
          int hp = (pxe/15 + kk/3)*17 + (pxe%15) + (kk%3);
          bf16x8 bh = ldu16x8(&gh[hp*RS + q*8]);
          bf16x8 bl = ldu16x8(&gl[hp*RS + q*8]);
          acc[0][ti] = __builtin_amdgcn_mfma_f32_16x16x32_bf16(ah0, bh, acc[0][ti], 0, 0, 0);
          acc[0][ti] = __builtin_amdgcn_mfma_f32_16x16x32_bf16(ah0, bl, acc[0][ti], 0, 0, 0);
          acc[0][ti] = __builtin_amdgcn_mfma_f32_16x16x32_bf16(al0, bh, acc[0][ti], 0, 0, 0);
          acc[1][ti] = __builtin_amdgcn_mfma_f32_16x16x32_bf16(ah1, bh, acc[1][ti], 0, 0, 0);
          acc[1][ti] = __builtin_amdgcn_mfma_f32_16x16x32_bf16(ah1, bl, acc[1][ti], 0, 0, 0);
          acc[1][ti] = __builtin_amdgcn_mfma_f32_16x16x32_bf16(al1, bh, acc[1][ti], 0, 0, 0);
        }
      }
    }
  }
  #pragma unroll
  for (int ot = 0; ot < 2; ot++){
    #pragma unroll
    for (int ti = 0; ti < 4; ti++){
      if (ti < ntl){
        int px = (tb + ti)*16 + l15;
        if (px < 225){
          #pragma unroll
          for (int r = 0; r < 4; r++){
            int o = (og0 + ot)*16 + q*4 + r;
            float v = eluf(acc[ot][ti][r] + bias[o]);
            out[((long long)b*64 + o)*225 + px] = v;
          }
        }
      }
    }
  }
}

// ---------------- convT2m (64->32, s=2, p=1, 15x15 -> 29x29, +elu) via parity-decomposed bf16 MFMA ----------------
// Output in PARITY-CLASS layout: t2m[b][o][841] = [ee 225 | eo 210 | oe 210 | oo 196].
// RS=44 (16-bank spread) + b64 operand loads, same as convT3m.
__global__ __launch_bounds__(256)
void convt2m_mfma(const float* __restrict__ in, const unsigned short* __restrict__ wbhi,
                  const unsigned short* __restrict__ wblo, const float* __restrict__ bias,
                  float* __restrict__ out)
{
  constexpr int RS = 44;                 // u16 per hp row: 32 ch + 12 pad
  __shared__ __align__(16) unsigned short gh[256*RS];
  __shared__ __align__(16) unsigned short gl[256*RS];
  const int b  = blockIdx.x;
  const int z  = blockIdx.y;
  const int t  = threadIdx.x;
  const int lane = t & 63, wv = t >> 6;
  const int l15 = lane & 15, q = lane >> 4;
  const int g = z*4 + wv;                // global wave id 0..7; tiles g + 8*i, i<7
  f32x4 acc[2][7];
  #pragma unroll
  for (int og = 0; og < 2; og++)
    #pragma unroll
    for (int i = 0; i < 7; i++) acc[og][i] = (f32x4){0.f,0.f,0.f,0.f};
  {
    unsigned* zg = (unsigned*)gh; unsigned* zl = (unsigned*)gl;
    for (int idx = t; idx < 256*RS/2; idx += 256){ zg[idx] = 0u; zl[idx] = 0u; }
  }
  for (int cq = 0; cq < 2; cq++){
    __syncthreads();
    for (int idx = t; idx < 16*225; idx += 256){
      int c2 = idx / 225, px = idx % 225;
      int c = 2*c2;
      const float* ip = in + ((long long)b*64 + cq*32 + c)*225 + px;
      float f0 = ip[0];
      float f1 = ip[225];
      unsigned h0 = bf16r(f0); unsigned l0 = bf16r(f0 - __uint_as_float(h0<<16));
      unsigned h1 = bf16r(f1); unsigned l1 = bf16r(f1 - __uint_as_float(h1<<16));
      int hp = (px/15)*16 + (px%15);
      *(unsigned*)&gh[hp*RS + c] = h0 | (h1<<16);
      *(unsigned*)&gl[hp*RS + c] = l0 | (l1<<16);
    }
    __syncthreads();
    #pragma unroll
    for (int i = 0; i < 7; i++){
      int T = g + i*8;
      int cls, tt;
      if (T < 15){ cls = 0; tt = T; }
      else if (T < 29){ cls = 1; tt = T - 15; }
      else if (T < 43){ cls = 2; tt = T - 29; }
      else { cls = 3; tt = T - 43; }
      int np = (cls == 0) ? 225 : (cls == 3) ? 196 : 210;
      int Wd = (cls == 0 || cls == 2) ? 15 : 14;
      int p = tt*16 + l15;
      int pe = p < np ? p : np - 1;
      int m = pe / Wd, n = pe % Wd;
      int hp0 = m*16 + n;
      int ry = (cls < 2) ? 1 : 2;
      int rx = ((cls & 1) == 0) ? 1 : 2;
      for (int jy = 0; jy < ry; jy++){
        int wky = (cls < 2) ? 1 : (jy == 0 ? 2 : 0);
        int shy = (cls < 2) ? 0 : (jy == 0 ? 0 : 16);
        for (int jx = 0; jx < rx; jx++){
          int wkx = ((cls & 1) == 0) ? 1 : (jx == 0 ? 2 : 0);
          int shx = ((cls & 1) == 0) ? 0 : (jx == 0 ? 0 : 1);
          int kk = wky*3 + wkx;
          int hp = hp0 + shy + shx;
          bf16x8 bh = ldu16x8(&gh[hp*RS + q*8]);
          bf16x8 bl = ldu16x8(&gl[hp*RS + q*8]);
          const long long wo = ((long long)kk*32)*64 + cq*32 + q*8;
          bf16x8 ah0 = *(const bf16x8*)&wbhi[wo + (long long)l15*64];
          bf16x8 al0 = *(const bf16x8*)&wblo[wo + (long long)l15*64];
          bf16x8 ah1 = *(const bf16x8*)&wbhi[wo + (long long)(16 + l15)*64];
          bf16x8 al1 = *(const bf16x8*)&wblo[wo + (long long)(16 + l15)*64];
          acc[0][i] = __builtin_amdgcn_mfma_f32_16x16x32_bf16(ah0, bh, acc[0][i], 0, 0, 0);
          acc[0][i] = __builtin_amdgcn_mfma_f32_16x16x32_bf16(ah0, bl, acc[0][i], 0, 0, 0);
          acc[0][i] = __builtin_amdgcn_mfma_f32_16x16x32_bf16(al0, bh, acc[0][i], 0, 0, 0);
          acc[1][i] = __builtin_amdgcn_mfma_f32_16x16x32_bf16(ah1, bh, acc[1][i], 0, 0, 0);
          acc[1][i] = __builtin_amdgcn_mfma_f32_16x16x32_bf16(ah1, bl, acc[1][i], 0, 0, 0);
          acc[1][i] = __builtin_amdgcn_mfma_f32_16x16x32_bf16(al1, bh, acc[1][i], 0, 0, 0);
        }
      }
    }
  }
  // epilogue: elu(acc + bias) -> class-layout out[b][o][clsOff + p], coalesced
  #pragma unroll
  for (int i = 0; i < 7; i++){
    int T = g + i*8;
    int cls, tt;
    if (T < 15){ cls = 0; tt = T; }
    else if (T < 29){ cls = 1; tt = T - 15; }
    else if (T < 43){ cls = 2; tt = T - 29; }
    else { cls = 3; tt = T - 43; }
    int np = (cls == 0) ? 225 : (cls == 3) ? 196 : 210;
    int clsOff = (cls == 0) ? 0 : (cls == 1) ? 225 : (cls == 2) ? 435 : 645;
    int p = tt*16 + l15;
    if (p < np){
      #pragma unroll
      for (int og = 0; og < 2; og++){
        #pragma unroll
        for (int r = 0; r < 4; r++){
          int o = og*16 + q*4 + r;
          float v = eluf(acc[og][i][r] + bias[o]);
          out[((long long)b*32 + o)*841 + clsOff + p] = v;
        }
      }
    }
  }
}

// ---------------- convT1m (32->2, k=2, s=1, PP=0), block-per-image LDS ----------------
__global__ __launch_bounds__(256)
void convt1m_lds_kernel(const float* __restrict__ in, const float* __restrict__ w,
                        const float* __restrict__ bias, float* __restrict__ out)
{
  __shared__ float simg[32*841];   // 107,648 B
  __shared__ float wl[256];        // w[32][2][2][2]
  const int b = blockIdx.x, t = threadIdx.x;
  for (int i = t; i < 32*841; i += 256) simg[i] = in[(long long)b*32*841 + i];
  if (t < 256) wl[t] = w[t];
  __syncthreads();
  const float* bsrc = simg;
  for (int i = t; i < 1568; i += 256){
    int x = i % 28; int r = i / 28;
    int y = r % 28; int o = r / 28;
    float acc = bias[o];
    #pragma unroll
    for (int ky = 0; ky < 2; ky++){
      int iy = y + ky;                 // PP=0
      int wky = 1 - ky;
      #pragma unroll
      for (int kx = 0; kx < 2; kx++){
        int ix = x + kx;               // PP=0
        int wkx = 1 - kx;
        int cls = (iy & 1)*2 + (ix & 1);
        int Wd  = (ix & 1) ? 14 : 15;
        int off = ((cls == 0) ? 0 : (cls == 1) ? 225 : (cls == 2) ? 435 : 645)
                + (iy >> 1)*Wd + (ix >> 1);
        const float* ip = bsrc + off;
        for (int c = 0; c < 32; c++){
          acc += wl[((c*2 + o)*2 + wky)*2 + wkx] * ip[c*841];
        }
      }
    }
    out[(long long)b*1568 + i] = eluf(acc);
  }
}

// ---------------- bn + elu + 2x2 avgpool (kept for bn3) ----------------
__global__ void bn_elu_pool_kernel(const float* __restrict__ in, const float* __restrict__ g,
                                   const float* __restrict__ bb, const float* __restrict__ sum,
                                   const float* __restrict__ sq, float* __restrict__ out,
                                   int B, int C, int H, int W, float invN)
{
  int Ho = H/2, Wo = W/2;
  int idx = blockIdx.x*256 + threadIdx.x;
  int total = B*C*Ho*Wo;
  if (idx >= total) return;
  int x = idx % Wo; int t = idx / Wo;
  int y = t % Ho;   t /= Ho;
  int c = t % C;    int b = t / C;
  float mean = sum[c]*invN;
  float var  = sq[c]*invN - mean*mean;
  float sc = g[c] * rsqrtf(var + 1e-5f);
  float sh = bb[c] - mean*sc;
  const float* p = in + (long long)(b*C + c)*H*W;
  float acc = 0.f;
  #pragma unroll
  for (int dy = 0; dy < 2; dy++)
    #pragma unroll
    for (int dx = 0; dx < 2; dx++)
      acc += eluf(sc*p[(2*y+dy)*W + (2*x+dx)] + sh);
  out[idx] = acc * 0.25f;
}

// ---------------- bn + elu in place (kept for bn41) ----------------
__global__ void bn_elu_inplace_kernel(float* __restrict__ xio, const float* __restrict__ g,
                                      const float* __restrict__ bb, const float* __restrict__ sum,
                                      const float* __restrict__ sq, int C, int HW, float invN, int total)
{
  int idx = blockIdx.x*256 + threadIdx.x;
  if (idx >= total) return;
  int c = (idx / HW) % C;
  float mean = sum[c]*invN;
  float var  = sq[c]*invN - mean*mean;
  float sc = g[c] * rsqrtf(var + 1e-5f);
  float sh = bb[c] - mean*sc;
  xio[idx] = eluf(sc*xio[idx] + sh);
}

// ---------------- final bicubic warp ----------------
__device__ __forceinline__ float cubicf(float A, float Bv, float C, float D, float t){
  float a = -0.5f*A + 1.5f*Bv - 1.5f*C + 0.5f*D;
  float b =  A - 2.5f*Bv + 2.0f*C - 0.5f*D;
  float c = -0.5f*A + 0.5f*C;
  return ((a*t + b)*t + c)*t + Bv;
}

__global__ void warp_kernel(const float* __restrict__ V, const float* __restrict__ x1,
                            float* __restrict__ out, int B)
{
  int idx = blockIdx.x*256 + threadIdx.x;
  int total = B*784;
  if (idx >= total) return;
  int j = idx % 28; int t = idx / 28;
  int i = t % 28;   int b = t / 28;
  float v0 = V[((long long)b*2 + 0)*784 + j*28 + i];
  float v1 = V[((long long)b*2 + 1)*784 + j*28 + i];
  float gx = (-1.f + 2.f*(float)j/27.f) + v0;
  float gy = (-1.f + 2.f*(float)i/27.f) + v1;
  float ix = (gx + 1.f)*13.5f;
  float iy = (gy + 1.f)*13.5f;
  float x0 = floorf(ix), y0 = floorf(iy);
  float tx = ix - x0, ty = iy - y0;
  const float* img = x1 + (long long)b*2*784;
  float rows[4];
  #pragma unroll
  for (int ky = -1; ky <= 2; ky++){
    int yi = (int)fminf(fmaxf(y0 + (float)ky, 0.f), 27.f);
    float cv[4];
    #pragma unroll
    for (int kx = -1; kx <= 2; kx++){
      int xi = (int)fminf(fmaxf(x0 + (float)kx, 0.f), 27.f);
      cv[kx+1] = img[yi*28 + xi];
    }
    rows[ky+1] = cubicf(cv[0], cv[1], cv[2], cv[3], tx);
  }
  out[idx] = cubicf(rows[0], rows[1], rows[2], rows[3], ty);
}

// ---------------- host ----------------
extern "C" void kernel_launch(void* const* d_in, const int* in_sizes, int n_in,
                              void* d_out, int out_size, void* d_ws, size_t ws_size,
                              hipStream_t stream)
{
  const int B = 256;
  const float* x1      = (const float*)d_in[0];
  const float* conv1_w = (const float*)d_in[9];
  const float* conv1_b = (const float*)d_in[10];
  const float* bn1_g   = (const float*)d_in[11];
  const float* bn1_b   = (const float*)d_in[12];
  const float* dc2_pw  = (const float*)d_in[13];
  const float* dc2_pb  = (const float*)d_in[14];
  const float* dc2_mw  = (const float*)d_in[15];
  const float* dc2_mb  = (const float*)d_in[16];
  const float* dc2_w   = (const float*)d_in[17];
  const float* bn2_g   = (const float*)d_in[18];
  const float* bn2_b   = (const float*)d_in[19];
  const float* conv3_w = (const float*)d_in[20];
  const float* conv3_b = (const float*)d_in[21];
  const float* bn3_g   = (const float*)d_in[22];
  const float* bn3_b   = (const float*)d_in[23];
  const float* dc41_pw = (const float*)d_in[24];
  const float* dc41_pb = (const float*)d_in[25];
  const float* dc41_mw = (const float*)d_in[26];
  const float* dc41_mb = (const float*)d_in[27];
  const float* dc41_w  = (const float*)d_in[28];
  const float* bn41_g  = (const float*)d_in[29];
  const float* bn41_b  = (const float*)d_in[30];
  const float* conv4_w = (const float*)d_in[31];
  const float* conv4_b = (const float*)d_in[32];
  const float* conv4m_w= (const float*)d_in[33];
  const float* conv4m_b= (const float*)d_in[34];
  const float* conv3m_w= (const float*)d_in[35];
  const float* conv3m_b= (const float*)d_in[36];
  const float* conv2m_w= (const float*)d_in[37];
  const float* conv2m_b= (const float*)d_in[38];
  const float* conv1m_w= (const float*)d_in[39];
  const float* conv1m_b= (const float*)d_in[40];

  float* ws = (float*)d_ws;

  // lifetime-packed arena (floats), stats in [0,1024).
  // cpart (conv1 stats partials, 32K floats) aliases p1 start: live [1]->[1.5] only,
  // consumed before conv1_pool writes p1 (stream-ordered). a2b at ws+AB, consumed at [6].
  // t2m (class layout) at AB+1048576: overlapped buffers dead by step [14].
  const long long AB = 1024;
  float* p1   = ws + AB;
  float* cpart= ws + AB;                // 2048*16 floats, [1]->[1.5]
  float* om2  = ws + AB + 3211264;
  float* a2   = ws + AB + 4566016;
  float* a3   = ws + AB + 10988544;
  float* p2   = ws + AB;
  float* om41 = ws + AB + 1605632;
  float* a41  = ws + AB + 1944320;
  float* a4   = ws + AB + 2747136;
  float* t4m  = ws + AB + 2772224;
  float* t3m  = ws + AB + 8310016;
  float* t2m  = ws + AB + 1048576;      // class layout [b][32][841]
  float* t1m  = ws + AB;
  unsigned int* a2b = (unsigned int*)(ws + AB);                     // 4,194,304 u32 (16.8MB)
  unsigned short* wb2f   = (unsigned short*)(ws + AB + 17411072);   // 81920 u16
  unsigned short* wb41f  = wb2f + 81920;                            // 81920 u16
  unsigned short* wb3mhi = (unsigned short*)(ws + AB + 17705984);   // 73728 u16 each
  unsigned short* wb3mlo = wb3mhi + 73728;
  unsigned short* wb3 = (unsigned short*)(ws + AB + 17779712);
  unsigned short* wb2mhi = (unsigned short*)(ws + AB);              // 18432 u16 each, low arena
  unsigned short* wb2mlo = wb2mhi + 18432;

  float* s1  = ws + 0;   float* q1  = ws + 64;
  float* s2  = ws + 128; float* q2  = ws + 256;
  float* s3  = ws + 384; float* q3  = ws + 512;
  float* s41 = ws + 640; float* q41 = ws + 704;

  auto nb = [](long long n){ return (int)((n + 255)/256); };

  hipMemsetAsync(d_ws, 0, 4096, stream);

  // weight pre-transposes / packs
  wconv3_bf16_kernel<<<nb(147456), 256, 0, stream>>>(conv3_w, wb3);
  wdeform_f16_kernel<<<nb(81920), 256, 0, stream>>>(dc2_w,  wb2f,  64, 128);
  wdeform_f16_kernel<<<nb(81920), 256, 0, stream>>>(dc41_w, wb41f, 128, 64);
  wconvt3m_split_kernel<<<nb(73728), 256, 0, stream>>>(conv3m_w, wb3mhi, wb3mlo);

  // [1] conv1 stats partials (no global atomics)
  conv1_stats<<<dim3(B,8), 256, 0, stream>>>(x1, conv1_w, conv1_b, cpart);
  // [1.5] reduce partials -> s1/q1
  conv1_reduce<<<1, 256, 0, stream>>>(cpart, s1, q1);
  // [2] conv1 recompute + bn1 + elu + avgpool -> p1 (LDS-staged coalesced out)
  conv1_pool<<<dim3(B,4), 256, 0, stream>>>(x1, conv1_w, conv1_b, bn1_g, bn1_b, s1, q1, p1);
  // [3] dc2 offsets (18, raw) + mask (9, sigmoid) fused -> om2; y-split x2, stage-once LDS
  offmask_tiled<64,14,14,2><<<dim3(B,2), 256, 0, stream>>>(p1, dc2_pw, dc2_pb, dc2_mw, dc2_mb, om2);
  // [4] deform conv 2 (64->128) -> a2 via fp16 MFMA, fused bn2 stats
  deform_mfma<64,128,14,14,49,4,4,2><<<dim3(B*4), 256, 0, stream>>>(p1, om2, wb2f, a2, s2, q2);
  // [5] bn2 + elu + bf16 pack into padded staging layout -> a2b
  bn2_pack_kernel<<<nb(4194304), 256, 0, stream>>>(a2, bn2_g, bn2_b, s2, q2, a2b);
  // [6] conv3 (128->128) -> a3 via bf16 MFMA, 64-o tile, fused bn3 stats
  conv3_mfma2<<<dim3(B,2), 256, 0, stream>>>((const unsigned short*)a2b, wb3, conv3_b, a3, s3, q3);
  // [7] bn3 + elu + avgpool -> p2
  bn_elu_pool_kernel<<<nb((long long)B*128*49), 256, 0, stream>>>(a3, bn3_g, bn3_b, s3, q3, p2,
                                                                  B, 128, 14, 14, 1.f/50176.f);
  // [8] dc41 offsets + mask fused -> om41; stage-once LDS, no per-channel barriers
  offmask_tiled<128,7,7,1><<<dim3(B,1), 256, 0, stream>>>(p2, dc41_pw, dc41_pb, dc41_mw, dc41_mb, om41);
  // [9] deform conv 41 (128->64) -> a41 via fp16 MFMA, fused bn41 stats
  deform_mfma<128,64,7,7,13,4,1,1><<<dim3(B*4), 256, 0, stream>>>(p2, om41, wb41f, a41, s41, q41);
  // [10] bn41 + elu
  bn_elu_inplace_kernel<<<nb((long long)B*64*49), 256, 0, stream>>>(a41, bn41_g, bn41_b, s41, q41,
                                                                    64, 49, 1.f/12544.f, B*64*49);
  // [10.5] convT2m weight pack into low arena (consumed at [14], before t1m at [15])
  wconvt2m_split_kernel<<<nb(18432), 256, 0, stream>>>(conv2m_w, wb2mhi, wb2mlo);
  // [11] conv4 (64->2, 7x7): block-per-image LDS kernel
  conv4_tiled<<<B, 256, 0, stream>>>(a41, conv4_w, conv4_b, a4);
  // [12] convT4m: 2->128, s=2, p=1, 7->13, parity-decomposed
  convt_s2_tiled<7,7,2,128,false><<<dim3(B,8), 256, 0, stream>>>(a4, conv4m_w, conv4m_b, t4m);
  // [13] convT3m: 128->64, 13->15 via split-precision bf16 MFMA, fused bias+elu -> t3m
  convt3m_mfma<<<dim3(B,2), 256, 0, stream>>>(t4m, wb3mhi, wb3mlo, conv3m_b, t3m);
  // [14] convT2m: 64->32, s=2, p=1, 15->29, +elu via parity-decomposed bf16 MFMA; class-layout out
  convt2m_mfma<<<dim3(B,2), 256, 0, stream>>>(t3m, wb2mhi, wb2mlo, conv2m_b, t2m);
  // [15] convT1m: 32->2, k=2, s=1, PP=0 taps, +elu; block-per-image LDS staging of class-layout t2m
  convt1m_lds_kernel<<<B, 256, 0, stream>>>(t2m, conv1m_w, conv1m_b, t1m);
  // [16] final warp
  warp_kernel<<<nb((long long)B*784), 256, 0, stream>>>(t1m, x1, (float*)d_out, B);
}